// Round 12
// baseline (867.405 us; speedup 1.0000x reference)
//
#include <hip/hip_runtime.h>
#include <hip/hip_bf16.h>
#include <math.h>

typedef __hip_bfloat16 bf16;
typedef short bf16x8 __attribute__((ext_vector_type(8)));
typedef float f32x4 __attribute__((ext_vector_type(4)));

__device__ inline short f2bs(float x) {
  bf16 h = __float2bfloat16(x);
  return *reinterpret_cast<short*>(&h);
}

// async global->LDS, 16B per lane, dest = wave-uniform base + lane*16
__device__ inline void gload16(const bf16* g, bf16* l) {
  __builtin_amdgcn_global_load_lds(
      (const __attribute__((address_space(1))) unsigned int*)g,
      (__attribute__((address_space(3))) unsigned int*)l, 16, 0, 0);
}

// ---------------- Threefry-2x32 (JAX-exact, 20 rounds) ----------------
__device__ inline void threefry2x32(unsigned k0, unsigned k1,
                                    unsigned x0, unsigned x1,
                                    unsigned& o0, unsigned& o1) {
  unsigned ks[3] = {k0, k1, k0 ^ k1 ^ 0x1BD11BDAu};
  const int rot[2][4] = {{13, 15, 26, 6}, {17, 29, 16, 24}};
  x0 += ks[0];
  x1 += ks[1];
  #pragma unroll
  for (int i = 0; i < 5; i++) {
    const int* r = rot[i & 1];
    #pragma unroll
    for (int j = 0; j < 4; j++) {
      x0 += x1;
      x1 = (x1 << r[j]) | (x1 >> (32 - r[j]));
      x1 ^= x0;
    }
    x0 += ks[(i + 1) % 3];
    x1 += ks[(i + 2) % 3] + (unsigned)(i + 1);
  }
  o0 = x0;
  o1 = x1;
}

__global__ void idx_kernel(int* __restrict__ idx, int L, int U, int layer) {
  int total = L * U, half = total / 2;
  int i = blockIdx.x * blockDim.x + threadIdx.x;
  if (i >= half) return;
  unsigned k0, k1;
  threefry2x32(0u, 42u, 0u, (unsigned)layer, k0, k1);
  unsigned o0, o1;
  threefry2x32(k0, k1, (unsigned)i, (unsigned)(half + i), o0, o1);
  idx[i] = (int)(o0 & (unsigned)(L - 1));
  idx[half + i] = (int)(o1 & (unsigned)(L - 1));
}

// ---------------- bf16 MFMA GEMM: BMxBN tile, BK=64, gload_lds + dbuf -------
// wave-tile (BM/2)x(BN/2); XOR-swizzled LDS (source-permute + read-permute).
template <int BM, int BN>
__global__ __launch_bounds__(256) void bgemm_t2(
    const bf16* __restrict__ A, const bf16* __restrict__ W,
    const float* __restrict__ bias, const float* __restrict__ R, int rmod,
    float* __restrict__ C, bf16* __restrict__ Cb,
    int M, int N, int K, int relu, int outmode) {
  constexpr int MR = BM / 32;
  constexpr int NR = BN / 32;
  __shared__ bf16 As[2][BM * 64];
  __shared__ bf16 Ws[2][BN * 64];
  int tid = threadIdx.x;
  int lane = tid & 63, w = tid >> 6;
  size_t row0 = (size_t)blockIdx.x * BM, col0 = (size_t)blockIdx.y * BN;
  int lr = lane >> 3;
  int scol = ((lane & 7) ^ lr) << 3;      // swizzled source col (elems)
  int srowA = w * (BM / 4) + lr;
  int srowW = w * (BN / 4) + lr;
  const bf16* agA = A + (row0 + srowA) * K + scol;
  const bf16* agW = W + (col0 + srowW) * K + scol;
  int dbA = (w * (BM / 4)) * 64;          // wave-uniform LDS base (elems)
  int dbW = (w * (BN / 4)) * 64;
  int wr = (w >> 1) * (BM / 2), wc = (w & 1) * (BN / 2);
  int fr = lane & 15;
  int fkb = ((lane >> 4) << 3) << 1;      // frag col-byte base {0,16,32,48}
  f32x4 acc[MR][NR] = {};
  int nt = K >> 6;
  #pragma unroll
  for (int i = 0; i < BM / 32; i++) gload16(agA + i * 8 * K, As[0] + dbA + i * 512);
  #pragma unroll
  for (int i = 0; i < BN / 32; i++) gload16(agW + i * 8 * K, Ws[0] + dbW + i * 512);
  int cur = 0;
  for (int t = 0; t < nt; t++) {
    __syncthreads();   // drains vmcnt -> buf[cur] staged
    if (t + 1 < nt) {
      int ko = (t + 1) << 6;
      #pragma unroll
      for (int i = 0; i < BM / 32; i++)
        gload16(agA + i * 8 * K + ko, As[cur ^ 1] + dbA + i * 512);
      #pragma unroll
      for (int i = 0; i < BN / 32; i++)
        gload16(agW + i * 8 * K + ko, Ws[cur ^ 1] + dbW + i * 512);
    }
    const char* ab = (const char*)As[cur];
    const char* wb = (const char*)Ws[cur];
    bf16x8 af[MR][2], bfv[NR][2];
    #pragma unroll
    for (int m = 0; m < MR; m++) {
      int row = wr + m * 16 + fr;
      int xr = (row & 7) << 4;
      #pragma unroll
      for (int kk = 0; kk < 2; kk++)
        af[m][kk] = *(const bf16x8*)(ab + row * 128 + ((fkb + kk * 64) ^ xr));
    }
    #pragma unroll
    for (int n = 0; n < NR; n++) {
      int row = wc + n * 16 + fr;
      int xr = (row & 7) << 4;
      #pragma unroll
      for (int kk = 0; kk < 2; kk++)
        bfv[n][kk] = *(const bf16x8*)(wb + row * 128 + ((fkb + kk * 64) ^ xr));
    }
    #pragma unroll
    for (int m = 0; m < MR; m++)
      #pragma unroll
      for (int n = 0; n < NR; n++) {
        acc[m][n] = __builtin_amdgcn_mfma_f32_16x16x32_bf16(af[m][0], bfv[n][0], acc[m][n], 0, 0, 0);
        acc[m][n] = __builtin_amdgcn_mfma_f32_16x16x32_bf16(af[m][1], bfv[n][1], acc[m][n], 0, 0, 0);
      }
    cur ^= 1;
  }
  int cr = (lane >> 4) << 2;
  int cc0 = lane & 15;
  #pragma unroll
  for (int m = 0; m < MR; m++) {
    #pragma unroll
    for (int n = 0; n < NR; n++) {
      #pragma unroll
      for (int r = 0; r < 4; r++) {
        size_t rr = row0 + wr + m * 16 + cr + r;
        size_t cc = col0 + wc + n * 16 + cc0;
        float v = acc[m][n][r];
        if (bias) v += bias[cc];
        if (R) v += rmod ? R[(rr % rmod) * N + cc] : R[rr * N + cc];
        if (relu) v = fmaxf(v, 0.f);
        if (outmode != 2) C[rr * N + cc] = v;
        if (outmode) Cb[rr * N + cc] = __float2bfloat16(v);
      }
    }
  }
}

// ---------------- fused per-layer weight cast --------------------------------
__global__ void castw_kernel(const float* __restrict__ wq, const float* __restrict__ wk,
                             const float* __restrict__ wv, const float* __restrict__ wo,
                             const float* __restrict__ c1, const float* __restrict__ c2,
                             bf16* __restrict__ wqkv, bf16* __restrict__ wob,
                             bf16* __restrict__ c1b, bf16* __restrict__ c2b) {
  int i = blockIdx.x * 256 + threadIdx.x;
  if (i >= 786432) return;
  const float* s;
  bf16* d;
  int j;
  if (i < 196608) {
    s = (i < 65536) ? wq : (i < 131072) ? wk : wv;
    float4 v = ((const float4*)s)[i & 65535];
    d = wqkv + (size_t)i * 4;
    d[0] = __float2bfloat16(v.x); d[1] = __float2bfloat16(v.y);
    d[2] = __float2bfloat16(v.z); d[3] = __float2bfloat16(v.w);
    return;
  }
  if (i < 262144) { s = wo; j = i - 196608; d = wob + (size_t)j * 4; }
  else if (i < 524288) { s = c1; j = i - 262144; d = c1b + (size_t)j * 4; }
  else { s = c2; j = i - 524288; d = c2b + (size_t)j * 4; }
  float4 v = ((const float4*)s)[j];
  d[0] = __float2bfloat16(v.x); d[1] = __float2bfloat16(v.y);
  d[2] = __float2bfloat16(v.z); d[3] = __float2bfloat16(v.w);
}

__global__ void catb3_kernel(const float* __restrict__ a, const float* __restrict__ b,
                             const float* __restrict__ c, float* __restrict__ d) {
  int i = blockIdx.x * 256 + threadIdx.x;
  if (i >= 1536) return;
  d[i] = (i < 512) ? a[i] : (i < 1024) ? b[i - 512] : c[i - 1024];
}

// dcw [o][c][k] -> wcol[o][k*512+c] bf16
__global__ void wperm_kernel(const float* __restrict__ w, bf16* __restrict__ wcol) {
  int i = blockIdx.x * 256 + threadIdx.x;
  if (i >= 512 * 1536) return;
  int o = i / 1536, r = i % 1536, k = r / 512, c = r % 512;
  wcol[i] = __float2bfloat16(w[o * 1536 + c * 3 + k]);
}

// tok_w [o][c][k] (c<64,k<3) -> [o][k*64+c] bf16
__global__ void tokperm_kernel(const float* __restrict__ w, bf16* __restrict__ d) {
  int i = blockIdx.x * 256 + threadIdx.x;
  if (i >= 512 * 192) return;
  int o = i / 192, r = i % 192, k = r / 64, c = r % 64;
  d[i] = __float2bfloat16(w[o * 192 + c * 3 + k]);
}

// PE table [1024][512] fp32
__global__ void pe_kernel(float* __restrict__ PE) {
  int t = blockIdx.x, o = threadIdx.x;
  int i2 = o >> 1;
  float div = expf((float)(2 * i2) * (-9.210340371976184f / 512.f));
  float ang = (float)t * div;
  PE[t * 512 + o] = (o & 1) ? cosf(ang) : sinf(ang);
}

// embedding im2col: x_enc -> [B*L, 192] bf16 (j = k*64+c), +1e-10
__global__ void im2col_e_kernel(const float* __restrict__ x, bf16* __restrict__ d,
                                int B, int L) {
  size_t i = (size_t)blockIdx.x * 256 + threadIdx.x;
  if (i >= (size_t)B * L * 192) return;
  int j = (int)(i % 192);
  size_t row = i / 192;
  int k = j >> 6, c = j & 63;
  int t = (int)(row % L), b = (int)(row / L);
  int ts = (t - 1 + k) & (L - 1);
  d[i] = __float2bfloat16(x[((size_t)(b * L + ts)) * 64 + c] + 1e-10f);
}

// ---------------- sparsity measure M: XCD-pinned, 8-lane-per-u dots ---------
__global__ __launch_bounds__(256) void sparsity_kernel(
    const float* __restrict__ QKV, const int* __restrict__ idx,
    float* __restrict__ M, int B, int H, int L, int U) {
  int tpb = L >> 2;
  int xcd = blockIdx.x & 7, slot = blockIdx.x >> 3;
  int bh = xcd + ((slot / tpb) << 3);
  int tb = slot % tpb;
  int wave = threadIdx.x >> 6;
  int t = tb * 4 + wave;
  int lane = threadIdx.x & 63;
  int h = bh & 7, b = bh >> 3;
  int ul = lane >> 3;
  int j = lane & 7;
  const float* qrow = QKV + ((size_t)(b * L + t)) * 1536 + h * 64 + j * 8;
  float4 qa = *(const float4*)qrow;
  float4 qb = *(const float4*)(qrow + 4);
  const float* kbase = QKV + (size_t)b * L * 1536 + 512 + h * 64 + j * 8;
  const int* irow = idx + t * U;
  float mx = -INFINITY, sm = 0.f;
  int iters = (U + 7) >> 3;
  for (int i = 0; i < iters; i++) {
    int u = i * 8 + ul;
    bool valid = (u < U);
    int kt = valid ? irow[u] : 0;
    const float* kr = kbase + (size_t)kt * 1536;
    float4 ka = *(const float4*)kr;
    float4 kb = *(const float4*)(kr + 4);
    float part = qa.x * ka.x + qa.y * ka.y + qa.z * ka.z + qa.w * ka.w +
                 qb.x * kb.x + qb.y * kb.y + qb.z * kb.z + qb.w * kb.w;
    #pragma unroll
    for (int off = 1; off < 8; off <<= 1) part += __shfl_xor(part, off);
    if (valid) { mx = fmaxf(mx, part); sm += part; }
  }
  #pragma unroll
  for (int off = 8; off < 64; off <<= 1) {
    mx = fmaxf(mx, __shfl_xor(mx, off));
    sm += __shfl_xor(sm, off);
  }
  if (lane == 0) M[(size_t)bh * L + t] = mx - sm / (float)L;
}

// ---------------- top-k: 1024 threads/block, value-in-register argmax -------
__global__ __launch_bounds__(1024) void topk_kernel(
    const float* __restrict__ M, int* __restrict__ top, int L, int U) {
  __shared__ float wv[16];
  __shared__ int wi[16];
  __shared__ int best_s;
  int bh = blockIdx.x, tid = threadIdx.x;
  int lane = tid & 63, w = tid >> 6;
  float v = (tid < L) ? M[(size_t)bh * L + tid] : -INFINITY;
  int myt = tid;
  for (int it = 0; it < U; it++) {
    float bv = v;
    int bi = myt;
    #pragma unroll
    for (int off = 32; off; off >>= 1) {
      float ov = __shfl_xor(bv, off);
      int oi = __shfl_xor(bi, off);
      if (ov > bv || (ov == bv && oi < bi)) { bv = ov; bi = oi; }
    }
    if (lane == 0) { wv[w] = bv; wi[w] = bi; }
    __syncthreads();
    if (w == 0) {
      float v2 = (lane < 16) ? wv[lane] : -INFINITY;
      int i2 = (lane < 16) ? wi[lane] : 0x7fffffff;
      #pragma unroll
      for (int off = 8; off; off >>= 1) {
        float ov = __shfl_xor(v2, off);
        int oi = __shfl_xor(i2, off);
        if (ov > v2 || (ov == v2 && oi < i2)) { v2 = ov; i2 = oi; }
      }
      if (lane == 0) { best_s = i2; top[bh * U + it] = i2; }
    }
    __syncthreads();
    if (myt == best_s) v = -INFINITY;
  }
}

// ---------------- V mean: deterministic 2-stage (QKV stride 1536) -----------
__global__ __launch_bounds__(512) void vmean_part_kernel(
    const float* __restrict__ QKV, float* __restrict__ VP, int L, int segs) {
  int b = blockIdx.x, s = blockIdx.y, c = threadIdx.x;
  int per = L / segs;
  const float* vb = QKV + ((size_t)(b * L + s * per)) * 1536 + 1024 + c;
  float acc = 0.f;
  for (int t = 0; t < per; t++) acc += vb[(size_t)t * 1536];
  VP[((size_t)(b * segs + s)) * 512 + c] = acc;
}

__global__ void vmean_reduce_kernel(const float* __restrict__ VP, float* __restrict__ Vmean,
                                    int segs, int L) {
  int i = blockIdx.x * 256 + threadIdx.x;
  if (i >= 8 * 512) return;
  int b = i >> 9, c = i & 511;
  float acc = 0.f;
  for (int s = 0; s < segs; s++) acc += VP[((size_t)(b * segs + s)) * 512 + c];
  Vmean[i] = acc / (float)L;
}

// ---------------- broadcast ctx = Vmean (bf16 out) ---------------------------
__global__ void bcast_ctx_kernel(const float* __restrict__ Vmean, bf16* __restrict__ ATTb,
                                 int B, int L) {
  size_t i = (size_t)blockIdx.x * 256 + threadIdx.x;
  if (i >= (size_t)B * L * 512) return;
  int c = (int)(i % 512);
  int b = (int)(i / ((size_t)512 * L));
  ATTb[i] = __float2bfloat16(Vmean[b * 512 + c]);
}

// ---------------- split-K MFMA flash attention: partial pass ----------------
__global__ __launch_bounds__(256) void attn_partial_kernel(
    const float* __restrict__ QKV, const int* __restrict__ top,
    float* __restrict__ PCTX, float* __restrict__ PML,
    int B, int H, int L, int U, int SPLIT) {
  __shared__ short q_lds[64 * 72];
  __shared__ short k_lds[64 * 72];
  __shared__ short vt_lds[64 * 72];
  __shared__ short p_lds[4][16 * 72];
  int bh = blockIdx.x / SPLIT;
  int sp = blockIdx.x % SPLIT;
  int KS = L / SPLIT;
  int h = bh & 7, b = bh >> 3;
  int tid = threadIdx.x;
  int lane = tid & 63, w = tid >> 6;
  int r = tid >> 2, q4 = tid & 3, c0 = q4 << 4;
  int fr = lane & 15, fk = (lane >> 4) << 3, g = lane >> 4;

  {
    short tmp[16];
    if (r < U) {
      int tq = top[bh * U + r];
      const float* src = QKV + ((size_t)(b * L + tq)) * 1536 + h * 64 + c0;
      #pragma unroll
      for (int i = 0; i < 4; i++) {
        float4 v = ((const float4*)src)[i];
        tmp[i * 4 + 0] = f2bs(v.x); tmp[i * 4 + 1] = f2bs(v.y);
        tmp[i * 4 + 2] = f2bs(v.z); tmp[i * 4 + 3] = f2bs(v.w);
      }
    } else {
      #pragma unroll
      for (int i = 0; i < 16; i++) tmp[i] = 0;
    }
    *(bf16x8*)&q_lds[r * 72 + c0] = *(bf16x8*)&tmp[0];
    *(bf16x8*)&q_lds[r * 72 + c0 + 8] = *(bf16x8*)&tmp[8];
  }
  __syncthreads();
  bf16x8 aq0 = *(const bf16x8*)&q_lds[(w * 16 + fr) * 72 + fk];
  bf16x8 aq1 = *(const bf16x8*)&q_lds[(w * 16 + fr) * 72 + 32 + fk];

  f32x4 ctx[4] = {};
  float m_run[4], l_run[4];
  #pragma unroll
  for (int i = 0; i < 4; i++) { m_run[i] = -INFINITY; l_run[i] = 0.f; }

  for (int t0 = sp * KS; t0 < sp * KS + KS; t0 += 64) {
    __syncthreads();
    {
      const float* ks = QKV + ((size_t)(b * L + t0 + r)) * 1536 + 512 + h * 64 + c0;
      const float* vs = ks + 512;
      short kt[16];
      #pragma unroll
      for (int i = 0; i < 4; i++) {
        float4 v = ((const float4*)ks)[i];
        kt[i * 4 + 0] = f2bs(v.x); kt[i * 4 + 1] = f2bs(v.y);
        kt[i * 4 + 2] = f2bs(v.z); kt[i * 4 + 3] = f2bs(v.w);
      }
      *(bf16x8*)&k_lds[r * 72 + c0] = *(bf16x8*)&kt[0];
      *(bf16x8*)&k_lds[r * 72 + c0 + 8] = *(bf16x8*)&kt[8];
      #pragma unroll
      for (int i = 0; i < 4; i++) {
        float4 v = ((const float4*)vs)[i];
        vt_lds[(c0 + i * 4 + 0) * 72 + r] = f2bs(v.x);
        vt_lds[(c0 + i * 4 + 1) * 72 + r] = f2bs(v.y);
        vt_lds[(c0 + i * 4 + 2) * 72 + r] = f2bs(v.z);
        vt_lds[(c0 + i * 4 + 3) * 72 + r] = f2bs(v.w);
      }
    }
    __syncthreads();
    f32x4 s[4];
    #pragma unroll
    for (int n = 0; n < 4; n++) {
      bf16x8 b0 = *(const bf16x8*)&k_lds[(n * 16 + fr) * 72 + fk];
      bf16x8 b1 = *(const bf16x8*)&k_lds[(n * 16 + fr) * 72 + 32 + fk];
      f32x4 z = {};
      z = __builtin_amdgcn_mfma_f32_16x16x32_bf16(aq0, b0, z, 0, 0, 0);
      s[n] = __builtin_amdgcn_mfma_f32_16x16x32_bf16(aq1, b1, z, 0, 0, 0);
    }
    #pragma unroll
    for (int n = 0; n < 4; n++)
      #pragma unroll
      for (int rg = 0; rg < 4; rg++) s[n][rg] *= 0.125f;
    #pragma unroll
    for (int rg = 0; rg < 4; rg++) {
      float tm = fmaxf(fmaxf(s[0][rg], s[1][rg]), fmaxf(s[2][rg], s[3][rg]));
      #pragma unroll
      for (int off = 1; off < 16; off <<= 1) tm = fmaxf(tm, __shfl_xor(tm, off));
      float mnew = fmaxf(m_run[rg], tm);
      float sc_old = expf(m_run[rg] - mnew);
      float rowsum = 0.f;
      #pragma unroll
      for (int n = 0; n < 4; n++) {
        float p = expf(s[n][rg] - mnew);
        s[n][rg] = p;
        rowsum += p;
      }
      #pragma unroll
      for (int off = 1; off < 16; off <<= 1) rowsum += __shfl_xor(rowsum, off);
      l_run[rg] = l_run[rg] * sc_old + rowsum;
      m_run[rg] = mnew;
      #pragma unroll
      for (int nd = 0; nd < 4; nd++) ctx[nd][rg] *= sc_old;
    }
    short* pw = p_lds[w];
    #pragma unroll
    for (int n = 0; n < 4; n++)
      #pragma unroll
      for (int rg = 0; rg < 4; rg++)
        pw[(g * 4 + rg) * 72 + n * 16 + fr] = f2bs(s[n][rg]);
    bf16x8 pa0 = *(const bf16x8*)&pw[fr * 72 + fk];
    bf16x8 pa1 = *(const bf16x8*)&pw[fr * 72 + 32 + fk];
    #pragma unroll
    for (int nd = 0; nd < 4; nd++) {
      bf16x8 v0 = *(const bf16x8*)&vt_lds[(nd * 16 + fr) * 72 + fk];
      bf16x8 v1 = *(const bf16x8*)&vt_lds[(nd * 16 + fr) * 72 + 32 + fk];
      ctx[nd] = __builtin_amdgcn_mfma_f32_16x16x32_bf16(pa0, v0, ctx[nd], 0, 0, 0);
      ctx[nd] = __builtin_amdgcn_mfma_f32_16x16x32_bf16(pa1, v1, ctx[nd], 0, 0, 0);
    }
  }
  #pragma unroll
  for (int rg = 0; rg < 4; rg++) {
    int qq = w * 16 + g * 4 + rg;
    if (qq < U) {
      size_t base = ((size_t)bh * SPLIT + sp) * 64 + qq;
      #pragma unroll
      for (int nd = 0; nd < 4; nd++)
        PCTX[base * 64 + nd * 16 + fr] = ctx[nd][rg];
      if (fr == 0) {
        PML[base * 2] = m_run[rg];
        PML[base * 2 + 1] = l_run[rg];
      }
    }
  }
}

// ---------------- split-K combine: merge SPLIT partials, write ATTb ---------
__global__ __launch_bounds__(256) void attn_combine_kernel(
    const float* __restrict__ PCTX, const float* __restrict__ PML,
    const int* __restrict__ top, bf16* __restrict__ ATTb,
    int B, int H, int L, int U, int SPLIT) {
  int bh = blockIdx.x;
  int row = blockIdx.y * 4 + (threadIdx.x >> 6);
  int d = threadIdx.x & 63;
  if (row >= U) return;
  int h = bh & 7, b = bh >> 3;
  float mstar = -INFINITY;
  for (int sp = 0; sp < SPLIT; sp++)
    mstar = fmaxf(mstar, PML[(((size_t)bh * SPLIT + sp) * 64 + row) * 2]);
  float lstar = 0.f, cacc = 0.f;
  for (int sp = 0; sp < SPLIT; sp++) {
    size_t base = ((size_t)bh * SPLIT + sp) * 64 + row;
    float m = PML[base * 2], lv = PML[base * 2 + 1];
    float wgt = expf(m - mstar);
    lstar += lv * wgt;
    cacc += PCTX[base * 64 + d] * wgt;
  }
  int tq = top[bh * U + row];
  ATTb[((size_t)(b * L + tq)) * 512 + h * 64 + d] = __float2bfloat16(cacc / lstar);
}

// ---------------- row LayerNorm (shuffle-reduce, 2 barriers) -----------------
__global__ __launch_bounds__(256) void ln_kernel(
    const float* __restrict__ Xin, const float* __restrict__ g,
    const float* __restrict__ bta, float* __restrict__ Xout,
    bf16* __restrict__ Xoutb, int rows) {
  __shared__ float part[8];
  int r = blockIdx.x, tid = threadIdx.x;
  int lane = tid & 63, w = tid >> 6;
  const float* xr = Xin + (size_t)r * 512;
  float v0 = xr[tid], v1 = xr[tid + 256];
  float s = v0 + v1;
  #pragma unroll
  for (int off = 1; off < 64; off <<= 1) s += __shfl_xor(s, off);
  if (lane == 0) part[w] = s;
  __syncthreads();
  float mean = (part[0] + part[1] + part[2] + part[3]) * (1.f / 512.f);
  float d0 = v0 - mean, d1 = v1 - mean;
  float q = d0 * d0 + d1 * d1;
  #pragma unroll
  for (int off = 1; off < 64; off <<= 1) q += __shfl_xor(q, off);
  if (lane == 0) part[4 + w] = q;
  __syncthreads();
  float var = (part[4] + part[5] + part[6] + part[7]) * (1.f / 512.f);
  float rs = rsqrtf(var + 1e-5f);
  float o0 = d0 * rs * g[tid] + bta[tid];
  float o1 = d1 * rs * g[tid + 256] + bta[tid + 256];
  float* out = Xout + (size_t)r * 512;
  out[tid] = o0;
  out[tid + 256] = o1;
  if (Xoutb) {
    Xoutb[(size_t)r * 512 + tid] = __float2bfloat16(o0);
    Xoutb[(size_t)r * 512 + tid + 256] = __float2bfloat16(o1);
  }
}

// ---------------- im2col for k=3 circular conv (bf16 out) -------------------
__global__ void im2col_kernel(const float* __restrict__ X, bf16* __restrict__ XCOL,
                              int B, int L) {
  size_t i = (size_t)blockIdx.x * 256 + threadIdx.x;
  size_t total = (size_t)B * L * 1536;
  if (i >= total) return;
  int c = (int)(i % 512);
  int k = (int)((i / 512) % 3);
  size_t row = i / 1536;
  int t = (int)(row % L), b = (int)(row / L);
  int ts = (t - 1 + k + L) % L;
  XCOL[i] = __float2bfloat16(X[((size_t)(b * L + ts)) * 512 + c]);
}

// ---------------- BatchNorm stats -------------------------------------------
__global__ void zero_kernel(float* p, int n) {
  int i = blockIdx.x * 256 + threadIdx.x;
  if (i < n) p[i] = 0.f;
}

__global__ __launch_bounds__(256) void bnstat_kernel(
    const float* __restrict__ Y, float* __restrict__ acc, int rows) {
  int tid = threadIdx.x;
  int c0 = tid, c1 = tid + 256;
  float s0 = 0, s1 = 0, q0 = 0, q1 = 0;
  for (int r = blockIdx.x; r < rows; r += gridDim.x) {
    float v0 = Y[(size_t)r * 512 + c0];
    float v1 = Y[(size_t)r * 512 + c1];
    s0 += v0; q0 += v0 * v0;
    s1 += v1; q1 += v1 * v1;
  }
  atomicAdd(&acc[c0], s0);
  atomicAdd(&acc[c1], s1);
  atomicAdd(&acc[512 + c0], q0);
  atomicAdd(&acc[512 + c1], q1);
}

// ---------------- fused BN + ELU + MaxPool(3,2,1) (+bf16 out) ---------------
__global__ void bnpool_kernel(const float* __restrict__ Y, const float* __restrict__ acc,
                              const float* __restrict__ g, const float* __restrict__ be,
                              float* __restrict__ Xout, bf16* __restrict__ Xoutb,
                              int B, int L, int rows) {
  int Lout = L / 2;
  size_t i = (size_t)blockIdx.x * 256 + threadIdx.x;
  if (i >= (size_t)B * Lout * 512) return;
  int c = (int)(i % 512);
  size_t orow = i / 512;
  int to = (int)(orow % Lout), b = (int)(orow / Lout);
  float mu = acc[c] / (float)rows;
  float var = acc[512 + c] / (float)rows - mu * mu;
  float rs = rsqrtf(var + 1e-5f) * g[c];
  float mx = -INFINITY;
  #pragma unroll
  for (int dj = -1; dj <= 1; dj++) {
    int j = 2 * to + dj;
    if (j < 0 || j >= L) continue;
    float v = (Y[((size_t)(b * L + j)) * 512 + c] - mu) * rs + be[c];
    v = v > 0.f ? v : expm1f(v);
    mx = fmaxf(mx, v);
  }
  Xout[i] = mx;
  Xoutb[i] = __float2bfloat16(mx);
}

// ---------------- final mean over rows: 2-stage ------------------------------
__global__ void meanrows_part_kernel(const float* __restrict__ Xin, float* __restrict__ MP,
                                     int L, int segs) {
  int b = blockIdx.x, s = blockIdx.y, d = threadIdx.x;
  int per = L / segs;
  const float* base = Xin + ((size_t)(b * L + s * per)) * 512 + d;
  float acc = 0.f;
  for (int t = 0; t < per; t++) acc += base[(size_t)t * 512];
  MP[((size_t)(b * segs + s)) * 512 + d] = acc;
}

__global__ void meanrows_red_kernel(const float* __restrict__ MP, float* __restrict__ out,
                                    int segs, int L) {
  int i = blockIdx.x * 256 + threadIdx.x;
  if (i >= 8 * 512) return;
  int b = i >> 9, c = i & 511;
  float acc = 0.f;
  for (int s = 0; s < segs; s++) acc += MP[((size_t)(b * segs + s)) * 512 + c];
  out[i] = acc / (float)L;
}

// ============================================================================
extern "C" void kernel_launch(void* const* d_in, const int* in_sizes, int n_in,
                              void* d_out, int out_size, void* d_ws, size_t ws_size,
                              hipStream_t stream) {
  const float* x_enc = (const float*)d_in[0];
  const float* tok_w = (const float*)d_in[1];
  const float* Wq = (const float*)d_in[2];
  const float* bq = (const float*)d_in[3];
  const float* Wk = (const float*)d_in[4];
  const float* bk = (const float*)d_in[5];
  const float* Wv = (const float*)d_in[6];
  const float* bv = (const float*)d_in[7];
  const float* Wo = (const float*)d_in[8];
  const float* bo = (const float*)d_in[9];
  const float* c1w = (const float*)d_in[10];
  const float* c1b = (const float*)d_in[11];
  const float* c2w = (const float*)d_in[12];
  const float* c2b = (const float*)d_in[13];
  const float* n1g = (const float*)d_in[14];
  const float* n1b = (const float*)d_in[15];
  const float* n2g = (const float*)d_in[16];
  const float* n2b = (const float*)d_in[17];
  const float* dcw = (const float*)d_in[18];
  const float* dcb = (const float*)d_in[19];
  const float* bng = (const float*)d_in[20];
  const float* bnb = (const float*)d_in[21];
  const float* fng = (const float*)d_in[22];
  const float* fnb = (const float*)d_in[23];

  const int B = 8, H = 8;
  const size_t NX = 4194304;  // 8*1024*512

  float* ws = (float*)d_ws;
  float* X    = ws;
  float* XLN  = ws + NX;                 // dead during attention -> PART bufs
  float* PCTX = XLN;
  float* PML  = XLN + 2097152;
  float* QKVf = ws + 2 * NX;
  bf16* H2b   = (bf16*)(ws + 2 * NX);
  float* Yc   = ws + 2 * NX;
  bf16* XCOLb = (bf16*)(ws + 4 * NX);
  bf16* INb   = (bf16*)(ws + 5 * NX);
  bf16* ATTb  = (bf16*)(ws + 5 * NX + NX / 2);
  float* WB   = ws + 6 * NX;
  bf16* WQKVb = (bf16*)(WB);
  bf16* Wob  = (bf16*)(WB + 393216);
  bf16* c1wb = (bf16*)(WB + 524288);
  bf16* c2wb = (bf16*)(WB + 1048576);
  bf16* wcvb = (bf16*)(WB + 1572864);
  bf16* tokwb = (bf16*)(WB + 1966080);
  float* PE   = WB + 2015232;
  float* MBUF = PE + 524288;
  float* VMEAN = MBUF + 65536;
  float* BNACC = VMEAN + 4096;
  int* IDX = (int*)(BNACC + 1024);
  int* TOP = IDX + 35840;
  float* VPART = (float*)(TOP + 2240);
  float* BQKV = VPART + 131072;

  // ---- embedding as GEMM (fused bf16 cast via outmode=1) ----
  pe_kernel<<<1024, 512, 0, stream>>>(PE);
  tokperm_kernel<<<(512 * 192 + 255) / 256, 256, 0, stream>>>(tok_w, tokwb);
  im2col_e_kernel<<<(int)(((size_t)B * 1024 * 192 + 255) / 256), 256, 0, stream>>>(
      x_enc, INb, B, 1024);
  bgemm_t2<64, 64><<<dim3(128, 8), 256, 0, stream>>>(INb, tokwb, nullptr, PE, 1024,
                                                     X, INb, 8192, 512, 192, 0, 1);

  int L = 1024;
  for (int l = 0; l < 3; l++) {
    int U = (L == 256) ? 30 : 35;
    int SPLIT = (L >= 512) ? 8 : 4;
    int rows = B * L;
    dim3 g64(rows / 64, 8);

    castw_kernel<<<3072, 256, 0, stream>>>(
        Wq + (size_t)l * 262144, Wk + (size_t)l * 262144, Wv + (size_t)l * 262144,
        Wo + (size_t)l * 262144, c1w + (size_t)l * 1048576, c2w + (size_t)l * 1048576,
        WQKVb, Wob, c1wb, c2wb);
    catb3_kernel<<<6, 256, 0, stream>>>(bq + l * 512, bk + l * 512, bv + l * 512, BQKV);
    if (l < 2)
      wperm_kernel<<<3072, 256, 0, stream>>>(dcw + (size_t)l * 786432, wcvb);

    // merged QKV projection: [rows,1536] (128^2 tile)
    bgemm_t2<128, 128><<<dim3(rows / 128, 12), 256, 0, stream>>>(
        INb, WQKVb, BQKV, nullptr, 0, QKVf, nullptr, rows, 1536, 512, 0, 0);

    int half = L * U / 2;
    idx_kernel<<<(half + 255) / 256, 256, 0, stream>>>(IDX, L, U, l);
    sparsity_kernel<<<(B * H * L) / 4, 256, 0, stream>>>(QKVf, IDX, MBUF, B, H, L, U);
    topk_kernel<<<B * H, 1024, 0, stream>>>(MBUF, TOP, L, U);
    vmean_part_kernel<<<dim3(B, 32), 512, 0, stream>>>(QKVf, VPART, L, 32);
    vmean_reduce_kernel<<<16, 256, 0, stream>>>(VPART, VMEAN, 32, L);
    bcast_ctx_kernel<<<(rows * 512) / 256, 256, 0, stream>>>(VMEAN, ATTb, B, L);
    attn_partial_kernel<<<B * H * SPLIT, 256, 0, stream>>>(
        QKVf, TOP, PCTX, PML, B, H, L, U, SPLIT);
    attn_combine_kernel<<<dim3(B * H, (U + 3) / 4), 256, 0, stream>>>(
        PCTX, PML, TOP, ATTb, B, H, L, U, SPLIT);

    bgemm_t2<64, 64><<<g64, 256, 0, stream>>>(ATTb, Wob, bo + l * 512, X, 0,
                                              X, nullptr, rows, 512, 512, 0, 0);
    ln_kernel<<<rows, 256, 0, stream>>>(X, n1g + l * 512, n1b + l * 512, XLN, INb, rows);
    // FFN1 (128^2 tile)
    bgemm_t2<128, 128><<<dim3(rows / 128, 16), 256, 0, stream>>>(
        INb, c1wb, c1b + l * 2048, nullptr, 0, nullptr, H2b, rows, 2048, 512, 1, 2);
    bgemm_t2<64, 64><<<g64, 256, 0, stream>>>(H2b, c2wb, c2b + l * 512, XLN, 0,
                                              X, nullptr, rows, 512, 2048, 0, 0);
    ln_kernel<<<rows, 256, 0, stream>>>(X, n2g + l * 512, n2b + l * 512, X, nullptr, rows);

    if (l < 2) {
      im2col_kernel<<<(int)(((size_t)rows * 1536) / 256), 256, 0, stream>>>(X, XCOLb, B, L);
      bgemm_t2<64, 64><<<g64, 256, 0, stream>>>(XCOLb, wcvb, dcb + l * 512, nullptr, 0,
                                                Yc, nullptr, rows, 512, 1536, 0, 0);
      zero_kernel<<<4, 256, 0, stream>>>(BNACC, 1024);
      bnstat_kernel<<<128, 256, 0, stream>>>(Yc, BNACC, rows);
      bnpool_kernel<<<(rows / 2 * 512) / 256, 256, 0, stream>>>(
          Yc, BNACC, bng + l * 512, bnb + l * 512, X, INb, B, L, rows);
      L >>= 1;
    }
  }

  int rowsF = B * L;  // L = 256
  ln_kernel<<<rowsF, 256, 0, stream>>>(X, fng, fnb, XLN, nullptr, rowsF);
  meanrows_part_kernel<<<dim3(8, 8), 512, 0, stream>>>(XLN, VPART, L, 8);
  meanrows_red_kernel<<<16, 256, 0, stream>>>(VPART, (float*)d_out, 8, L);
}

// Round 13
// 849.314 us; speedup vs baseline: 1.0213x; 1.0213x over previous
//
#include <hip/hip_runtime.h>
#include <hip/hip_bf16.h>
#include <math.h>

typedef __hip_bfloat16 bf16;
typedef short bf16x8 __attribute__((ext_vector_type(8)));
typedef float f32x4 __attribute__((ext_vector_type(4)));

__device__ inline short f2bs(float x) {
  bf16 h = __float2bfloat16(x);
  return *reinterpret_cast<short*>(&h);
}

// async global->LDS, 16B per lane, dest = wave-uniform base + lane*16
__device__ inline void gload16(const bf16* g, bf16* l) {
  __builtin_amdgcn_global_load_lds(
      (const __attribute__((address_space(1))) unsigned int*)g,
      (__attribute__((address_space(3))) unsigned int*)l, 16, 0, 0);
}

// ---------------- Threefry-2x32 (JAX-exact, 20 rounds) ----------------
__device__ inline void threefry2x32(unsigned k0, unsigned k1,
                                    unsigned x0, unsigned x1,
                                    unsigned& o0, unsigned& o1) {
  unsigned ks[3] = {k0, k1, k0 ^ k1 ^ 0x1BD11BDAu};
  const int rot[2][4] = {{13, 15, 26, 6}, {17, 29, 16, 24}};
  x0 += ks[0];
  x1 += ks[1];
  #pragma unroll
  for (int i = 0; i < 5; i++) {
    const int* r = rot[i & 1];
    #pragma unroll
    for (int j = 0; j < 4; j++) {
      x0 += x1;
      x1 = (x1 << r[j]) | (x1 >> (32 - r[j]));
      x1 ^= x0;
    }
    x0 += ks[(i + 1) % 3];
    x1 += ks[(i + 2) % 3] + (unsigned)(i + 1);
  }
  o0 = x0;
  o1 = x1;
}

__global__ void idx_kernel(int* __restrict__ idx, int L, int U, int layer) {
  int total = L * U, half = total / 2;
  int i = blockIdx.x * blockDim.x + threadIdx.x;
  if (i >= half) return;
  unsigned k0, k1;
  threefry2x32(0u, 42u, 0u, (unsigned)layer, k0, k1);
  unsigned o0, o1;
  threefry2x32(k0, k1, (unsigned)i, (unsigned)(half + i), o0, o1);
  idx[i] = (int)(o0 & (unsigned)(L - 1));
  idx[half + i] = (int)(o1 & (unsigned)(L - 1));
}

// ---------------- bf16 MFMA GEMM: BMxBN tile, BK=64, gload_lds + dbuf -------
// wave-tile (BM/2)x(BN/2); XOR-swizzled LDS (source-permute + read-permute).
template <int BM, int BN>
__global__ __launch_bounds__(256) void bgemm_t2(
    const bf16* __restrict__ A, const bf16* __restrict__ W,
    const float* __restrict__ bias, const float* __restrict__ R, int rmod,
    float* __restrict__ C, bf16* __restrict__ Cb,
    int M, int N, int K, int relu, int outmode) {
  constexpr int MR = BM / 32;
  constexpr int NR = BN / 32;
  __shared__ bf16 As[2][BM * 64];
  __shared__ bf16 Ws[2][BN * 64];
  int tid = threadIdx.x;
  int lane = tid & 63, w = tid >> 6;
  size_t row0 = (size_t)blockIdx.x * BM, col0 = (size_t)blockIdx.y * BN;
  int lr = lane >> 3;
  int scol = ((lane & 7) ^ lr) << 3;      // swizzled source col (elems)
  int srowA = w * (BM / 4) + lr;
  int srowW = w * (BN / 4) + lr;
  const bf16* agA = A + (row0 + srowA) * K + scol;
  const bf16* agW = W + (col0 + srowW) * K + scol;
  int dbA = (w * (BM / 4)) * 64;          // wave-uniform LDS base (elems)
  int dbW = (w * (BN / 4)) * 64;
  int wr = (w >> 1) * (BM / 2), wc = (w & 1) * (BN / 2);
  int fr = lane & 15;
  int fkb = ((lane >> 4) << 3) << 1;      // frag col-byte base {0,16,32,48}
  f32x4 acc[MR][NR] = {};
  int nt = K >> 6;
  #pragma unroll
  for (int i = 0; i < BM / 32; i++) gload16(agA + i * 8 * K, As[0] + dbA + i * 512);
  #pragma unroll
  for (int i = 0; i < BN / 32; i++) gload16(agW + i * 8 * K, Ws[0] + dbW + i * 512);
  int cur = 0;
  for (int t = 0; t < nt; t++) {
    __syncthreads();   // drains vmcnt -> buf[cur] staged
    if (t + 1 < nt) {
      int ko = (t + 1) << 6;
      #pragma unroll
      for (int i = 0; i < BM / 32; i++)
        gload16(agA + i * 8 * K + ko, As[cur ^ 1] + dbA + i * 512);
      #pragma unroll
      for (int i = 0; i < BN / 32; i++)
        gload16(agW + i * 8 * K + ko, Ws[cur ^ 1] + dbW + i * 512);
    }
    const char* ab = (const char*)As[cur];
    const char* wb = (const char*)Ws[cur];
    bf16x8 af[MR][2], bfv[NR][2];
    #pragma unroll
    for (int m = 0; m < MR; m++) {
      int row = wr + m * 16 + fr;
      int xr = (row & 7) << 4;
      #pragma unroll
      for (int kk = 0; kk < 2; kk++)
        af[m][kk] = *(const bf16x8*)(ab + row * 128 + ((fkb + kk * 64) ^ xr));
    }
    #pragma unroll
    for (int n = 0; n < NR; n++) {
      int row = wc + n * 16 + fr;
      int xr = (row & 7) << 4;
      #pragma unroll
      for (int kk = 0; kk < 2; kk++)
        bfv[n][kk] = *(const bf16x8*)(wb + row * 128 + ((fkb + kk * 64) ^ xr));
    }
    #pragma unroll
    for (int m = 0; m < MR; m++)
      #pragma unroll
      for (int n = 0; n < NR; n++) {
        acc[m][n] = __builtin_amdgcn_mfma_f32_16x16x32_bf16(af[m][0], bfv[n][0], acc[m][n], 0, 0, 0);
        acc[m][n] = __builtin_amdgcn_mfma_f32_16x16x32_bf16(af[m][1], bfv[n][1], acc[m][n], 0, 0, 0);
      }
    cur ^= 1;
  }
  int cr = (lane >> 4) << 2;
  int cc0 = lane & 15;
  #pragma unroll
  for (int m = 0; m < MR; m++) {
    #pragma unroll
    for (int n = 0; n < NR; n++) {
      #pragma unroll
      for (int r = 0; r < 4; r++) {
        size_t rr = row0 + wr + m * 16 + cr + r;
        size_t cc = col0 + wc + n * 16 + cc0;
        float v = acc[m][n][r];
        if (bias) v += bias[cc];
        if (R) v += rmod ? R[(rr % rmod) * N + cc] : R[rr * N + cc];
        if (relu) v = fmaxf(v, 0.f);
        if (outmode != 2) C[rr * N + cc] = v;
        if (outmode) Cb[rr * N + cc] = __float2bfloat16(v);
      }
    }
  }
}

// ---------------- fused per-layer weight cast --------------------------------
__global__ void castw_kernel(const float* __restrict__ wq, const float* __restrict__ wk,
                             const float* __restrict__ wv, const float* __restrict__ wo,
                             const float* __restrict__ c1, const float* __restrict__ c2,
                             bf16* __restrict__ wqkv, bf16* __restrict__ wob,
                             bf16* __restrict__ c1b, bf16* __restrict__ c2b) {
  int i = blockIdx.x * 256 + threadIdx.x;
  if (i >= 786432) return;
  const float* s;
  bf16* d;
  int j;
  if (i < 196608) {
    s = (i < 65536) ? wq : (i < 131072) ? wk : wv;
    float4 v = ((const float4*)s)[i & 65535];
    d = wqkv + (size_t)i * 4;
    d[0] = __float2bfloat16(v.x); d[1] = __float2bfloat16(v.y);
    d[2] = __float2bfloat16(v.z); d[3] = __float2bfloat16(v.w);
    return;
  }
  if (i < 262144) { s = wo; j = i - 196608; d = wob + (size_t)j * 4; }
  else if (i < 524288) { s = c1; j = i - 262144; d = c1b + (size_t)j * 4; }
  else { s = c2; j = i - 524288; d = c2b + (size_t)j * 4; }
  float4 v = ((const float4*)s)[j];
  d[0] = __float2bfloat16(v.x); d[1] = __float2bfloat16(v.y);
  d[2] = __float2bfloat16(v.z); d[3] = __float2bfloat16(v.w);
}

__global__ void catb3_kernel(const float* __restrict__ a, const float* __restrict__ b,
                             const float* __restrict__ c, float* __restrict__ d) {
  int i = blockIdx.x * 256 + threadIdx.x;
  if (i >= 1536) return;
  d[i] = (i < 512) ? a[i] : (i < 1024) ? b[i - 512] : c[i - 1024];
}

// dcw [o][c][k] -> wcol[o][k*512+c] bf16
__global__ void wperm_kernel(const float* __restrict__ w, bf16* __restrict__ wcol) {
  int i = blockIdx.x * 256 + threadIdx.x;
  if (i >= 512 * 1536) return;
  int o = i / 1536, r = i % 1536, k = r / 512, c = r % 512;
  wcol[i] = __float2bfloat16(w[o * 1536 + c * 3 + k]);
}

// tok_w [o][c][k] (c<64,k<3) -> [o][k*64+c] bf16
__global__ void tokperm_kernel(const float* __restrict__ w, bf16* __restrict__ d) {
  int i = blockIdx.x * 256 + threadIdx.x;
  if (i >= 512 * 192) return;
  int o = i / 192, r = i % 192, k = r / 64, c = r % 64;
  d[i] = __float2bfloat16(w[o * 192 + c * 3 + k]);
}

// PE table [1024][512] fp32
__global__ void pe_kernel(float* __restrict__ PE) {
  int t = blockIdx.x, o = threadIdx.x;
  int i2 = o >> 1;
  float div = expf((float)(2 * i2) * (-9.210340371976184f / 512.f));
  float ang = (float)t * div;
  PE[t * 512 + o] = (o & 1) ? cosf(ang) : sinf(ang);
}

// embedding im2col: x_enc -> [B*L, 192] bf16 (j = k*64+c), +1e-10
__global__ void im2col_e_kernel(const float* __restrict__ x, bf16* __restrict__ d,
                                int B, int L) {
  size_t i = (size_t)blockIdx.x * 256 + threadIdx.x;
  if (i >= (size_t)B * L * 192) return;
  int j = (int)(i % 192);
  size_t row = i / 192;
  int k = j >> 6, c = j & 63;
  int t = (int)(row % L), b = (int)(row / L);
  int ts = (t - 1 + k) & (L - 1);
  d[i] = __float2bfloat16(x[((size_t)(b * L + ts)) * 64 + c] + 1e-10f);
}

// ---------------- sparsity measure M: XCD-pinned, 8-lane-per-u dots ---------
__global__ __launch_bounds__(256) void sparsity_kernel(
    const float* __restrict__ QKV, const int* __restrict__ idx,
    float* __restrict__ M, int B, int H, int L, int U) {
  int tpb = L >> 2;
  int xcd = blockIdx.x & 7, slot = blockIdx.x >> 3;
  int bh = xcd + ((slot / tpb) << 3);
  int tb = slot % tpb;
  int wave = threadIdx.x >> 6;
  int t = tb * 4 + wave;
  int lane = threadIdx.x & 63;
  int h = bh & 7, b = bh >> 3;
  int ul = lane >> 3;
  int j = lane & 7;
  const float* qrow = QKV + ((size_t)(b * L + t)) * 1536 + h * 64 + j * 8;
  float4 qa = *(const float4*)qrow;
  float4 qb = *(const float4*)(qrow + 4);
  const float* kbase = QKV + (size_t)b * L * 1536 + 512 + h * 64 + j * 8;
  const int* irow = idx + t * U;
  float mx = -INFINITY, sm = 0.f;
  int iters = (U + 7) >> 3;
  for (int i = 0; i < iters; i++) {
    int u = i * 8 + ul;
    bool valid = (u < U);
    int kt = valid ? irow[u] : 0;
    const float* kr = kbase + (size_t)kt * 1536;
    float4 ka = *(const float4*)kr;
    float4 kb = *(const float4*)(kr + 4);
    float part = qa.x * ka.x + qa.y * ka.y + qa.z * ka.z + qa.w * ka.w +
                 qb.x * kb.x + qb.y * kb.y + qb.z * kb.z + qb.w * kb.w;
    #pragma unroll
    for (int off = 1; off < 8; off <<= 1) part += __shfl_xor(part, off);
    if (valid) { mx = fmaxf(mx, part); sm += part; }
  }
  #pragma unroll
  for (int off = 8; off < 64; off <<= 1) {
    mx = fmaxf(mx, __shfl_xor(mx, off));
    sm += __shfl_xor(sm, off);
  }
  if (lane == 0) M[(size_t)bh * L + t] = mx - sm / (float)L;
}

// ---------------- top-k: 1024 threads/block, value-in-register argmax -------
__global__ __launch_bounds__(1024) void topk_kernel(
    const float* __restrict__ M, int* __restrict__ top, int L, int U) {
  __shared__ float wv[16];
  __shared__ int wi[16];
  __shared__ int best_s;
  int bh = blockIdx.x, tid = threadIdx.x;
  int lane = tid & 63, w = tid >> 6;
  float v = (tid < L) ? M[(size_t)bh * L + tid] : -INFINITY;
  int myt = tid;
  for (int it = 0; it < U; it++) {
    float bv = v;
    int bi = myt;
    #pragma unroll
    for (int off = 32; off; off >>= 1) {
      float ov = __shfl_xor(bv, off);
      int oi = __shfl_xor(bi, off);
      if (ov > bv || (ov == bv && oi < bi)) { bv = ov; bi = oi; }
    }
    if (lane == 0) { wv[w] = bv; wi[w] = bi; }
    __syncthreads();
    if (w == 0) {
      float v2 = (lane < 16) ? wv[lane] : -INFINITY;
      int i2 = (lane < 16) ? wi[lane] : 0x7fffffff;
      #pragma unroll
      for (int off = 8; off; off >>= 1) {
        float ov = __shfl_xor(v2, off);
        int oi = __shfl_xor(i2, off);
        if (ov > v2 || (ov == v2 && oi < i2)) { v2 = ov; i2 = oi; }
      }
      if (lane == 0) { best_s = i2; top[bh * U + it] = i2; }
    }
    __syncthreads();
    if (myt == best_s) v = -INFINITY;
  }
}

// ---------------- V mean: deterministic 2-stage (QKV stride 1536) -----------
__global__ __launch_bounds__(512) void vmean_part_kernel(
    const float* __restrict__ QKV, float* __restrict__ VP, int L, int segs) {
  int b = blockIdx.x, s = blockIdx.y, c = threadIdx.x;
  int per = L / segs;
  const float* vb = QKV + ((size_t)(b * L + s * per)) * 1536 + 1024 + c;
  float acc = 0.f;
  for (int t = 0; t < per; t++) acc += vb[(size_t)t * 1536];
  VP[((size_t)(b * segs + s)) * 512 + c] = acc;
}

__global__ void vmean_reduce_kernel(const float* __restrict__ VP, float* __restrict__ Vmean,
                                    int segs, int L) {
  int i = blockIdx.x * 256 + threadIdx.x;
  if (i >= 8 * 512) return;
  int b = i >> 9, c = i & 511;
  float acc = 0.f;
  for (int s = 0; s < segs; s++) acc += VP[((size_t)(b * segs + s)) * 512 + c];
  Vmean[i] = acc / (float)L;
}

// ---------------- broadcast ctx = Vmean (bf16 out) ---------------------------
__global__ void bcast_ctx_kernel(const float* __restrict__ Vmean, bf16* __restrict__ ATTb,
                                 int B, int L) {
  size_t i = (size_t)blockIdx.x * 256 + threadIdx.x;
  if (i >= (size_t)B * L * 512) return;
  int c = (int)(i % 512);
  int b = (int)(i / ((size_t)512 * L));
  ATTb[i] = __float2bfloat16(Vmean[b * 512 + c]);
}

// ---------------- split-K MFMA flash attention: partial pass ----------------
__global__ __launch_bounds__(256) void attn_partial_kernel(
    const float* __restrict__ QKV, const int* __restrict__ top,
    float* __restrict__ PCTX, float* __restrict__ PML,
    int B, int H, int L, int U, int SPLIT) {
  __shared__ short q_lds[64 * 72];
  __shared__ short k_lds[64 * 72];
  __shared__ short vt_lds[64 * 72];
  __shared__ short p_lds[4][16 * 72];
  int bh = blockIdx.x / SPLIT;
  int sp = blockIdx.x % SPLIT;
  int KS = L / SPLIT;
  int h = bh & 7, b = bh >> 3;
  int tid = threadIdx.x;
  int lane = tid & 63, w = tid >> 6;
  int r = tid >> 2, q4 = tid & 3, c0 = q4 << 4;
  int fr = lane & 15, fk = (lane >> 4) << 3, g = lane >> 4;

  {
    short tmp[16];
    if (r < U) {
      int tq = top[bh * U + r];
      const float* src = QKV + ((size_t)(b * L + tq)) * 1536 + h * 64 + c0;
      #pragma unroll
      for (int i = 0; i < 4; i++) {
        float4 v = ((const float4*)src)[i];
        tmp[i * 4 + 0] = f2bs(v.x); tmp[i * 4 + 1] = f2bs(v.y);
        tmp[i * 4 + 2] = f2bs(v.z); tmp[i * 4 + 3] = f2bs(v.w);
      }
    } else {
      #pragma unroll
      for (int i = 0; i < 16; i++) tmp[i] = 0;
    }
    *(bf16x8*)&q_lds[r * 72 + c0] = *(bf16x8*)&tmp[0];
    *(bf16x8*)&q_lds[r * 72 + c0 + 8] = *(bf16x8*)&tmp[8];
  }
  __syncthreads();
  bf16x8 aq0 = *(const bf16x8*)&q_lds[(w * 16 + fr) * 72 + fk];
  bf16x8 aq1 = *(const bf16x8*)&q_lds[(w * 16 + fr) * 72 + 32 + fk];

  f32x4 ctx[4] = {};
  float m_run[4], l_run[4];
  #pragma unroll
  for (int i = 0; i < 4; i++) { m_run[i] = -INFINITY; l_run[i] = 0.f; }

  for (int t0 = sp * KS; t0 < sp * KS + KS; t0 += 64) {
    __syncthreads();
    {
      const float* ks = QKV + ((size_t)(b * L + t0 + r)) * 1536 + 512 + h * 64 + c0;
      const float* vs = ks + 512;
      short kt[16];
      #pragma unroll
      for (int i = 0; i < 4; i++) {
        float4 v = ((const float4*)ks)[i];
        kt[i * 4 + 0] = f2bs(v.x); kt[i * 4 + 1] = f2bs(v.y);
        kt[i * 4 + 2] = f2bs(v.z); kt[i * 4 + 3] = f2bs(v.w);
      }
      *(bf16x8*)&k_lds[r * 72 + c0] = *(bf16x8*)&kt[0];
      *(bf16x8*)&k_lds[r * 72 + c0 + 8] = *(bf16x8*)&kt[8];
      #pragma unroll
      for (int i = 0; i < 4; i++) {
        float4 v = ((const float4*)vs)[i];
        vt_lds[(c0 + i * 4 + 0) * 72 + r] = f2bs(v.x);
        vt_lds[(c0 + i * 4 + 1) * 72 + r] = f2bs(v.y);
        vt_lds[(c0 + i * 4 + 2) * 72 + r] = f2bs(v.z);
        vt_lds[(c0 + i * 4 + 3) * 72 + r] = f2bs(v.w);
      }
    }
    __syncthreads();
    f32x4 s[4];
    #pragma unroll
    for (int n = 0; n < 4; n++) {
      bf16x8 b0 = *(const bf16x8*)&k_lds[(n * 16 + fr) * 72 + fk];
      bf16x8 b1 = *(const bf16x8*)&k_lds[(n * 16 + fr) * 72 + 32 + fk];
      f32x4 z = {};
      z = __builtin_amdgcn_mfma_f32_16x16x32_bf16(aq0, b0, z, 0, 0, 0);
      s[n] = __builtin_amdgcn_mfma_f32_16x16x32_bf16(aq1, b1, z, 0, 0, 0);
    }
    #pragma unroll
    for (int n = 0; n < 4; n++)
      #pragma unroll
      for (int rg = 0; rg < 4; rg++) s[n][rg] *= 0.125f;
    #pragma unroll
    for (int rg = 0; rg < 4; rg++) {
      float tm = fmaxf(fmaxf(s[0][rg], s[1][rg]), fmaxf(s[2][rg], s[3][rg]));
      #pragma unroll
      for (int off = 1; off < 16; off <<= 1) tm = fmaxf(tm, __shfl_xor(tm, off));
      float mnew = fmaxf(m_run[rg], tm);
      float sc_old = expf(m_run[rg] - mnew);
      float rowsum = 0.f;
      #pragma unroll
      for (int n = 0; n < 4; n++) {
        float p = expf(s[n][rg] - mnew);
        s[n][rg] = p;
        rowsum += p;
      }
      #pragma unroll
      for (int off = 1; off < 16; off <<= 1) rowsum += __shfl_xor(rowsum, off);
      l_run[rg] = l_run[rg] * sc_old + rowsum;
      m_run[rg] = mnew;
      #pragma unroll
      for (int nd = 0; nd < 4; nd++) ctx[nd][rg] *= sc_old;
    }
    short* pw = p_lds[w];
    #pragma unroll
    for (int n = 0; n < 4; n++)
      #pragma unroll
      for (int rg = 0; rg < 4; rg++)
        pw[(g * 4 + rg) * 72 + n * 16 + fr] = f2bs(s[n][rg]);
    bf16x8 pa0 = *(const bf16x8*)&pw[fr * 72 + fk];
    bf16x8 pa1 = *(const bf16x8*)&pw[fr * 72 + 32 + fk];
    #pragma unroll
    for (int nd = 0; nd < 4; nd++) {
      bf16x8 v0 = *(const bf16x8*)&vt_lds[(nd * 16 + fr) * 72 + fk];
      bf16x8 v1 = *(const bf16x8*)&vt_lds[(nd * 16 + fr) * 72 + 32 + fk];
      ctx[nd] = __builtin_amdgcn_mfma_f32_16x16x32_bf16(pa0, v0, ctx[nd], 0, 0, 0);
      ctx[nd] = __builtin_amdgcn_mfma_f32_16x16x32_bf16(pa1, v1, ctx[nd], 0, 0, 0);
    }
  }
  #pragma unroll
  for (int rg = 0; rg < 4; rg++) {
    int qq = w * 16 + g * 4 + rg;
    if (qq < U) {
      size_t base = ((size_t)bh * SPLIT + sp) * 64 + qq;
      #pragma unroll
      for (int nd = 0; nd < 4; nd++)
        PCTX[base * 64 + nd * 16 + fr] = ctx[nd][rg];
      if (fr == 0) {
        PML[base * 2] = m_run[rg];
        PML[base * 2 + 1] = l_run[rg];
      }
    }
  }
}

// ---------------- split-K combine: merge SPLIT partials, write ATTb ---------
__global__ __launch_bounds__(256) void attn_combine_kernel(
    const float* __restrict__ PCTX, const float* __restrict__ PML,
    const int* __restrict__ top, bf16* __restrict__ ATTb,
    int B, int H, int L, int U, int SPLIT) {
  int bh = blockIdx.x;
  int row = blockIdx.y * 4 + (threadIdx.x >> 6);
  int d = threadIdx.x & 63;
  if (row >= U) return;
  int h = bh & 7, b = bh >> 3;
  float mstar = -INFINITY;
  for (int sp = 0; sp < SPLIT; sp++)
    mstar = fmaxf(mstar, PML[(((size_t)bh * SPLIT + sp) * 64 + row) * 2]);
  float lstar = 0.f, cacc = 0.f;
  for (int sp = 0; sp < SPLIT; sp++) {
    size_t base = ((size_t)bh * SPLIT + sp) * 64 + row;
    float m = PML[base * 2], lv = PML[base * 2 + 1];
    float wgt = expf(m - mstar);
    lstar += lv * wgt;
    cacc += PCTX[base * 64 + d] * wgt;
  }
  int tq = top[bh * U + row];
  ATTb[((size_t)(b * L + tq)) * 512 + h * 64 + d] = __float2bfloat16(cacc / lstar);
}

// ---------------- row LayerNorm (shuffle-reduce, 2 barriers) -----------------
__global__ __launch_bounds__(256) void ln_kernel(
    const float* __restrict__ Xin, const float* __restrict__ g,
    const float* __restrict__ bta, float* __restrict__ Xout,
    bf16* __restrict__ Xoutb, int rows) {
  __shared__ float part[8];
  int r = blockIdx.x, tid = threadIdx.x;
  int lane = tid & 63, w = tid >> 6;
  const float* xr = Xin + (size_t)r * 512;
  float v0 = xr[tid], v1 = xr[tid + 256];
  float s = v0 + v1;
  #pragma unroll
  for (int off = 1; off < 64; off <<= 1) s += __shfl_xor(s, off);
  if (lane == 0) part[w] = s;
  __syncthreads();
  float mean = (part[0] + part[1] + part[2] + part[3]) * (1.f / 512.f);
  float d0 = v0 - mean, d1 = v1 - mean;
  float q = d0 * d0 + d1 * d1;
  #pragma unroll
  for (int off = 1; off < 64; off <<= 1) q += __shfl_xor(q, off);
  if (lane == 0) part[4 + w] = q;
  __syncthreads();
  float var = (part[4] + part[5] + part[6] + part[7]) * (1.f / 512.f);
  float rs = rsqrtf(var + 1e-5f);
  float o0 = d0 * rs * g[tid] + bta[tid];
  float o1 = d1 * rs * g[tid + 256] + bta[tid + 256];
  float* out = Xout + (size_t)r * 512;
  out[tid] = o0;
  out[tid + 256] = o1;
  if (Xoutb) {
    Xoutb[(size_t)r * 512 + tid] = __float2bfloat16(o0);
    Xoutb[(size_t)r * 512 + tid + 256] = __float2bfloat16(o1);
  }
}

// ---------------- im2col for k=3 circular conv (bf16 out) -------------------
__global__ void im2col_kernel(const float* __restrict__ X, bf16* __restrict__ XCOL,
                              int B, int L) {
  size_t i = (size_t)blockIdx.x * 256 + threadIdx.x;
  size_t total = (size_t)B * L * 1536;
  if (i >= total) return;
  int c = (int)(i % 512);
  int k = (int)((i / 512) % 3);
  size_t row = i / 1536;
  int t = (int)(row % L), b = (int)(row / L);
  int ts = (t - 1 + k + L) % L;
  XCOL[i] = __float2bfloat16(X[((size_t)(b * L + ts)) * 512 + c]);
}

// ---------------- BatchNorm stats -------------------------------------------
__global__ void zero_kernel(float* p, int n) {
  int i = blockIdx.x * 256 + threadIdx.x;
  if (i < n) p[i] = 0.f;
}

__global__ __launch_bounds__(256) void bnstat_kernel(
    const float* __restrict__ Y, float* __restrict__ acc, int rows) {
  int tid = threadIdx.x;
  int c0 = tid, c1 = tid + 256;
  float s0 = 0, s1 = 0, q0 = 0, q1 = 0;
  for (int r = blockIdx.x; r < rows; r += gridDim.x) {
    float v0 = Y[(size_t)r * 512 + c0];
    float v1 = Y[(size_t)r * 512 + c1];
    s0 += v0; q0 += v0 * v0;
    s1 += v1; q1 += v1 * v1;
  }
  atomicAdd(&acc[c0], s0);
  atomicAdd(&acc[c1], s1);
  atomicAdd(&acc[512 + c0], q0);
  atomicAdd(&acc[512 + c1], q1);
}

// ---------------- fused BN + ELU + MaxPool(3,2,1) (+bf16 out) ---------------
__global__ void bnpool_kernel(const float* __restrict__ Y, const float* __restrict__ acc,
                              const float* __restrict__ g, const float* __restrict__ be,
                              float* __restrict__ Xout, bf16* __restrict__ Xoutb,
                              int B, int L, int rows) {
  int Lout = L / 2;
  size_t i = (size_t)blockIdx.x * 256 + threadIdx.x;
  if (i >= (size_t)B * Lout * 512) return;
  int c = (int)(i % 512);
  size_t orow = i / 512;
  int to = (int)(orow % Lout), b = (int)(orow / Lout);
  float mu = acc[c] / (float)rows;
  float var = acc[512 + c] / (float)rows - mu * mu;
  float rs = rsqrtf(var + 1e-5f) * g[c];
  float mx = -INFINITY;
  #pragma unroll
  for (int dj = -1; dj <= 1; dj++) {
    int j = 2 * to + dj;
    if (j < 0 || j >= L) continue;
    float v = (Y[((size_t)(b * L + j)) * 512 + c] - mu) * rs + be[c];
    v = v > 0.f ? v : expm1f(v);
    mx = fmaxf(mx, v);
  }
  Xout[i] = mx;
  Xoutb[i] = __float2bfloat16(mx);
}

// ---------------- final mean over rows: 2-stage ------------------------------
__global__ void meanrows_part_kernel(const float* __restrict__ Xin, float* __restrict__ MP,
                                     int L, int segs) {
  int b = blockIdx.x, s = blockIdx.y, d = threadIdx.x;
  int per = L / segs;
  const float* base = Xin + ((size_t)(b * L + s * per)) * 512 + d;
  float acc = 0.f;
  for (int t = 0; t < per; t++) acc += base[(size_t)t * 512];
  MP[((size_t)(b * segs + s)) * 512 + d] = acc;
}

__global__ void meanrows_red_kernel(const float* __restrict__ MP, float* __restrict__ out,
                                    int segs, int L) {
  int i = blockIdx.x * 256 + threadIdx.x;
  if (i >= 8 * 512) return;
  int b = i >> 9, c = i & 511;
  float acc = 0.f;
  for (int s = 0; s < segs; s++) acc += MP[((size_t)(b * segs + s)) * 512 + c];
  out[i] = acc / (float)L;
}

// ============================================================================
extern "C" void kernel_launch(void* const* d_in, const int* in_sizes, int n_in,
                              void* d_out, int out_size, void* d_ws, size_t ws_size,
                              hipStream_t stream) {
  const float* x_enc = (const float*)d_in[0];
  const float* tok_w = (const float*)d_in[1];
  const float* Wq = (const float*)d_in[2];
  const float* bq = (const float*)d_in[3];
  const float* Wk = (const float*)d_in[4];
  const float* bk = (const float*)d_in[5];
  const float* Wv = (const float*)d_in[6];
  const float* bv = (const float*)d_in[7];
  const float* Wo = (const float*)d_in[8];
  const float* bo = (const float*)d_in[9];
  const float* c1w = (const float*)d_in[10];
  const float* c1b = (const float*)d_in[11];
  const float* c2w = (const float*)d_in[12];
  const float* c2b = (const float*)d_in[13];
  const float* n1g = (const float*)d_in[14];
  const float* n1b = (const float*)d_in[15];
  const float* n2g = (const float*)d_in[16];
  const float* n2b = (const float*)d_in[17];
  const float* dcw = (const float*)d_in[18];
  const float* dcb = (const float*)d_in[19];
  const float* bng = (const float*)d_in[20];
  const float* bnb = (const float*)d_in[21];
  const float* fng = (const float*)d_in[22];
  const float* fnb = (const float*)d_in[23];

  const int B = 8, H = 8;
  const size_t NX = 4194304;  // 8*1024*512

  float* ws = (float*)d_ws;
  float* X    = ws;
  float* XLN  = ws + NX;                 // dead during attention -> PART bufs
  float* PCTX = XLN;
  float* PML  = XLN + 2097152;
  float* QKVf = ws + 2 * NX;
  bf16* H2b   = (bf16*)(ws + 2 * NX);
  float* Yc   = ws + 2 * NX;
  bf16* XCOLb = (bf16*)(ws + 4 * NX);
  bf16* INb   = (bf16*)(ws + 5 * NX);
  bf16* ATTb  = (bf16*)(ws + 5 * NX + NX / 2);
  float* WB   = ws + 6 * NX;
  bf16* WQKVb = (bf16*)(WB);
  bf16* Wob  = (bf16*)(WB + 393216);
  bf16* c1wb = (bf16*)(WB + 524288);
  bf16* c2wb = (bf16*)(WB + 1048576);
  bf16* wcvb = (bf16*)(WB + 1572864);
  bf16* tokwb = (bf16*)(WB + 1966080);
  float* PE   = WB + 2015232;
  float* MBUF = PE + 524288;
  float* VMEAN = MBUF + 65536;
  float* BNACC = VMEAN + 4096;
  int* IDX = (int*)(BNACC + 1024);
  int* TOP = IDX + 35840;
  float* VPART = (float*)(TOP + 2240);
  float* BQKV = VPART + 131072;

  // ---- embedding as GEMM (fused bf16 cast via outmode=1) ----
  pe_kernel<<<1024, 512, 0, stream>>>(PE);
  tokperm_kernel<<<(512 * 192 + 255) / 256, 256, 0, stream>>>(tok_w, tokwb);
  im2col_e_kernel<<<(int)(((size_t)B * 1024 * 192 + 255) / 256), 256, 0, stream>>>(
      x_enc, INb, B, 1024);
  bgemm_t2<64, 64><<<dim3(128, 8), 256, 0, stream>>>(INb, tokwb, nullptr, PE, 1024,
                                                     X, INb, 8192, 512, 192, 0, 1);

  int L = 1024;
  for (int l = 0; l < 3; l++) {
    int U = (L == 256) ? 30 : 35;
    int SPLIT = (L >= 512) ? 8 : 4;
    int rows = B * L;
    dim3 g64(rows / 64, 8);

    castw_kernel<<<3072, 256, 0, stream>>>(
        Wq + (size_t)l * 262144, Wk + (size_t)l * 262144, Wv + (size_t)l * 262144,
        Wo + (size_t)l * 262144, c1w + (size_t)l * 1048576, c2w + (size_t)l * 1048576,
        WQKVb, Wob, c1wb, c2wb);
    catb3_kernel<<<6, 256, 0, stream>>>(bq + l * 512, bk + l * 512, bv + l * 512, BQKV);
    if (l < 2)
      wperm_kernel<<<3072, 256, 0, stream>>>(dcw + (size_t)l * 786432, wcvb);

    // merged QKV projection: [rows,1536]  (64x128 tile: 3 blocks/CU, 16:12 ratio)
    bgemm_t2<64, 128><<<dim3(rows / 64, 12), 256, 0, stream>>>(
        INb, WQKVb, BQKV, nullptr, 0, QKVf, nullptr, rows, 1536, 512, 0, 0);

    int half = L * U / 2;
    idx_kernel<<<(half + 255) / 256, 256, 0, stream>>>(IDX, L, U, l);
    sparsity_kernel<<<(B * H * L) / 4, 256, 0, stream>>>(QKVf, IDX, MBUF, B, H, L, U);
    topk_kernel<<<B * H, 1024, 0, stream>>>(MBUF, TOP, L, U);
    vmean_part_kernel<<<dim3(B, 32), 512, 0, stream>>>(QKVf, VPART, L, 32);
    vmean_reduce_kernel<<<16, 256, 0, stream>>>(VPART, VMEAN, 32, L);
    bcast_ctx_kernel<<<(rows * 512) / 256, 256, 0, stream>>>(VMEAN, ATTb, B, L);
    attn_partial_kernel<<<B * H * SPLIT, 256, 0, stream>>>(
        QKVf, TOP, PCTX, PML, B, H, L, U, SPLIT);
    attn_combine_kernel<<<dim3(B * H, (U + 3) / 4), 256, 0, stream>>>(
        PCTX, PML, TOP, ATTb, B, H, L, U, SPLIT);

    bgemm_t2<64, 64><<<g64, 256, 0, stream>>>(ATTb, Wob, bo + l * 512, X, 0,
                                              X, nullptr, rows, 512, 512, 0, 0);
    ln_kernel<<<rows, 256, 0, stream>>>(X, n1g + l * 512, n1b + l * 512, XLN, INb, rows);
    // FFN1 (64x128 tile)
    bgemm_t2<64, 128><<<dim3(rows / 64, 16), 256, 0, stream>>>(
        INb, c1wb, c1b + l * 2048, nullptr, 0, nullptr, H2b, rows, 2048, 512, 1, 2);
    bgemm_t2<64, 64><<<g64, 256, 0, stream>>>(H2b, c2wb, c2b + l * 512, XLN, 0,
                                              X, nullptr, rows, 512, 2048, 0, 0);
    ln_kernel<<<rows, 256, 0, stream>>>(X, n2g + l * 512, n2b + l * 512, X, nullptr, rows);

    if (l < 2) {
      im2col_kernel<<<(int)(((size_t)rows * 1536) / 256), 256, 0, stream>>>(X, XCOLb, B, L);
      bgemm_t2<64, 64><<<g64, 256, 0, stream>>>(XCOLb, wcvb, dcb + l * 512, nullptr, 0,
                                                Yc, nullptr, rows, 512, 1536, 0, 0);
      zero_kernel<<<4, 256, 0, stream>>>(BNACC, 1024);
      bnstat_kernel<<<128, 256, 0, stream>>>(Yc, BNACC, rows);
      bnpool_kernel<<<(rows / 2 * 512) / 256, 256, 0, stream>>>(
          Yc, BNACC, bng + l * 512, bnb + l * 512, X, INb, B, L, rows);
      L >>= 1;
    }
  }

  int rowsF = B * L;  // L = 256
  ln_kernel<<<rowsF, 256, 0, stream>>>(X, fng, fnb, XLN, nullptr, rowsF);
  meanrows_part_kernel<<<dim3(8, 8), 512, 0, stream>>>(XLN, VPART, L, 8);
  meanrows_red_kernel<<<16, 256, 0, stream>>>(VPART, (float*)d_out, 8, L);
}

// Round 14
// 786.990 us; speedup vs baseline: 1.1022x; 1.0792x over previous
//
#include <hip/hip_runtime.h>
#include <hip/hip_bf16.h>
#include <math.h>

typedef __hip_bfloat16 bf16;
typedef short bf16x8 __attribute__((ext_vector_type(8)));
typedef float f32x4 __attribute__((ext_vector_type(4)));

__device__ inline short f2bs(float x) {
  bf16 h = __float2bfloat16(x);
  return *reinterpret_cast<short*>(&h);
}

// async global->LDS, 16B per lane, dest = wave-uniform base + lane*16
__device__ inline void gload16(const bf16* g, bf16* l) {
  __builtin_amdgcn_global_load_lds(
      (const __attribute__((address_space(1))) unsigned int*)g,
      (__attribute__((address_space(3))) unsigned int*)l, 16, 0, 0);
}

// ---------------- Threefry-2x32 (JAX-exact, 20 rounds) ----------------
__device__ inline void threefry2x32(unsigned k0, unsigned k1,
                                    unsigned x0, unsigned x1,
                                    unsigned& o0, unsigned& o1) {
  unsigned ks[3] = {k0, k1, k0 ^ k1 ^ 0x1BD11BDAu};
  const int rot[2][4] = {{13, 15, 26, 6}, {17, 29, 16, 24}};
  x0 += ks[0];
  x1 += ks[1];
  #pragma unroll
  for (int i = 0; i < 5; i++) {
    const int* r = rot[i & 1];
    #pragma unroll
    for (int j = 0; j < 4; j++) {
      x0 += x1;
      x1 = (x1 << r[j]) | (x1 >> (32 - r[j]));
      x1 ^= x0;
    }
    x0 += ks[(i + 1) % 3];
    x1 += ks[(i + 2) % 3] + (unsigned)(i + 1);
  }
  o0 = x0;
  o1 = x1;
}

__global__ void idx_kernel(int* __restrict__ idx, int L, int U, int layer) {
  int total = L * U, half = total / 2;
  int i = blockIdx.x * blockDim.x + threadIdx.x;
  if (i >= half) return;
  unsigned k0, k1;
  threefry2x32(0u, 42u, 0u, (unsigned)layer, k0, k1);
  unsigned o0, o1;
  threefry2x32(k0, k1, (unsigned)i, (unsigned)(half + i), o0, o1);
  idx[i] = (int)(o0 & (unsigned)(L - 1));
  idx[half + i] = (int)(o1 & (unsigned)(L - 1));
}

// ---------------- bf16 MFMA GEMM: 64x64 tile, BK=64, gload_lds + dbuf -------
__global__ __launch_bounds__(256) void bgemm_g(
    const bf16* __restrict__ A, const bf16* __restrict__ W,
    const float* __restrict__ bias, const float* __restrict__ R, int rmod,
    float* __restrict__ C, bf16* __restrict__ Cb,
    int M, int N, int K, int relu, int outmode) {
  __shared__ bf16 As[2][64 * 64];
  __shared__ bf16 Ws[2][64 * 64];
  int tid = threadIdx.x;
  int lane = tid & 63, w = tid >> 6;
  size_t row0 = (size_t)blockIdx.x * 64, col0 = (size_t)blockIdx.y * 64;
  int lr = lane >> 3;
  int scol = ((lane & 7) ^ lr) << 3;
  int srow = w * 16 + lr;
  const bf16* agA0 = A + (row0 + srow) * K + scol;
  const bf16* agA1 = A + (row0 + srow + 8) * K + scol;
  const bf16* agW0 = W + (col0 + srow) * K + scol;
  const bf16* agW1 = W + (col0 + srow + 8) * K + scol;
  int db0 = (w * 16) * 64;
  int db1 = db0 + 512;
  int wr = (w >> 1) << 5, wc = (w & 1) << 5;
  int fr = lane & 15;
  int fkb = ((lane >> 4) << 3) << 1;
  f32x4 acc[2][2] = {};
  int nt = K >> 6;
  gload16(agA0, As[0] + db0); gload16(agA1, As[0] + db1);
  gload16(agW0, Ws[0] + db0); gload16(agW1, Ws[0] + db1);
  int cur = 0;
  for (int t = 0; t < nt; t++) {
    __syncthreads();
    if (t + 1 < nt) {
      int ko = (t + 1) << 6;
      gload16(agA0 + ko, As[cur ^ 1] + db0); gload16(agA1 + ko, As[cur ^ 1] + db1);
      gload16(agW0 + ko, Ws[cur ^ 1] + db0); gload16(agW1 + ko, Ws[cur ^ 1] + db1);
    }
    const char* ab = (const char*)As[cur];
    const char* wb = (const char*)Ws[cur];
    bf16x8 af[2][2], bfv[2][2];
    #pragma unroll
    for (int m = 0; m < 2; m++) {
      int row = wr + m * 16 + fr;
      int xr = (row & 7) << 4;
      #pragma unroll
      for (int kk = 0; kk < 2; kk++)
        af[m][kk] = *(const bf16x8*)(ab + row * 128 + ((fkb + kk * 64) ^ xr));
    }
    #pragma unroll
    for (int n = 0; n < 2; n++) {
      int row = wc + n * 16 + fr;
      int xr = (row & 7) << 4;
      #pragma unroll
      for (int kk = 0; kk < 2; kk++)
        bfv[n][kk] = *(const bf16x8*)(wb + row * 128 + ((fkb + kk * 64) ^ xr));
    }
    #pragma unroll
    for (int m = 0; m < 2; m++)
      #pragma unroll
      for (int n = 0; n < 2; n++) {
        acc[m][n] = __builtin_amdgcn_mfma_f32_16x16x32_bf16(af[m][0], bfv[n][0], acc[m][n], 0, 0, 0);
        acc[m][n] = __builtin_amdgcn_mfma_f32_16x16x32_bf16(af[m][1], bfv[n][1], acc[m][n], 0, 0, 0);
      }
    cur ^= 1;
  }
  int cr = (lane >> 4) << 2;
  int cc0 = lane & 15;
  #pragma unroll
  for (int m = 0; m < 2; m++) {
    #pragma unroll
    for (int n = 0; n < 2; n++) {
      #pragma unroll
      for (int r = 0; r < 4; r++) {
        size_t rr = row0 + wr + m * 16 + cr + r;
        size_t cc = col0 + wc + n * 16 + cc0;
        float v = acc[m][n][r];
        if (bias) v += bias[cc];
        if (R) v += rmod ? R[(rr % rmod) * N + cc] : R[rr * N + cc];
        if (relu) v = fmaxf(v, 0.f);
        if (outmode != 2) C[rr * N + cc] = v;
        if (outmode) Cb[rr * N + cc] = __float2bfloat16(v);
      }
    }
  }
}

// ---------------- fused circular-conv GEMM: C = im2col(Xb) @ W^T + bias -----
// A-staging gathers Xb[b, (t-1+kk) mod L, c] directly (per-lane global addr).
__global__ __launch_bounds__(256) void bgemm_conv(
    const bf16* __restrict__ Xb, const bf16* __restrict__ W,
    const float* __restrict__ bias, float* __restrict__ C,
    int rows, int L) {
  const int K = 1536;
  __shared__ bf16 As[2][64 * 64];
  __shared__ bf16 Ws[2][64 * 64];
  int tid = threadIdx.x;
  int lane = tid & 63, w = tid >> 6;
  size_t row0 = (size_t)blockIdx.x * 64, col0 = (size_t)blockIdx.y * 64;
  int lr = lane >> 3;
  int scol = ((lane & 7) ^ lr) << 3;
  int srow = w * 16 + lr;
  int bb = (int)((row0 + srow) / L) * L;        // batch base (tile never crosses b)
  int tr0 = (int)((row0 + srow) % L);           // output t for issue 0
  int tr1 = tr0 + 8;                            // issue 1 (same b; < L)
  const bf16* agW0 = W + (col0 + srow) * K + scol;
  const bf16* agW1 = W + (col0 + srow + 8) * K + scol;
  int db0 = (w * 16) * 64;
  int db1 = db0 + 512;
  int wr = (w >> 1) << 5, wc = (w & 1) << 5;
  int fr = lane & 15;
  int fkb = ((lane >> 4) << 3) << 1;
  f32x4 acc[2][2] = {};
  const int nt = K >> 6;  // 24
  auto stageA = [&](int k0, bf16* dst) {
    int kk = k0 >> 9;
    int co = (k0 & 511) + scol;
    int ta = tr0 - 1 + kk;
    ta += (ta < 0) ? L : 0; ta -= (ta >= L) ? L : 0;
    int tb = tr1 - 1 + kk;
    tb -= (tb >= L) ? L : 0;
    gload16(Xb + ((size_t)(bb + ta)) * 512 + co, dst + db0);
    gload16(Xb + ((size_t)(bb + tb)) * 512 + co, dst + db1);
  };
  stageA(0, As[0]);
  gload16(agW0, Ws[0] + db0); gload16(agW1, Ws[0] + db1);
  int cur = 0;
  for (int t = 0; t < nt; t++) {
    __syncthreads();
    if (t + 1 < nt) {
      int ko = (t + 1) << 6;
      stageA(ko, As[cur ^ 1]);
      gload16(agW0 + ko, Ws[cur ^ 1] + db0); gload16(agW1 + ko, Ws[cur ^ 1] + db1);
    }
    const char* ab = (const char*)As[cur];
    const char* wb = (const char*)Ws[cur];
    bf16x8 af[2][2], bfv[2][2];
    #pragma unroll
    for (int m = 0; m < 2; m++) {
      int row = wr + m * 16 + fr;
      int xr = (row & 7) << 4;
      #pragma unroll
      for (int kk = 0; kk < 2; kk++)
        af[m][kk] = *(const bf16x8*)(ab + row * 128 + ((fkb + kk * 64) ^ xr));
    }
    #pragma unroll
    for (int n = 0; n < 2; n++) {
      int row = wc + n * 16 + fr;
      int xr = (row & 7) << 4;
      #pragma unroll
      for (int kk = 0; kk < 2; kk++)
        bfv[n][kk] = *(const bf16x8*)(wb + row * 128 + ((fkb + kk * 64) ^ xr));
    }
    #pragma unroll
    for (int m = 0; m < 2; m++)
      #pragma unroll
      for (int n = 0; n < 2; n++) {
        acc[m][n] = __builtin_amdgcn_mfma_f32_16x16x32_bf16(af[m][0], bfv[n][0], acc[m][n], 0, 0, 0);
        acc[m][n] = __builtin_amdgcn_mfma_f32_16x16x32_bf16(af[m][1], bfv[n][1], acc[m][n], 0, 0, 0);
      }
    cur ^= 1;
  }
  int cr = (lane >> 4) << 2;
  int cc0 = lane & 15;
  #pragma unroll
  for (int m = 0; m < 2; m++) {
    #pragma unroll
    for (int n = 0; n < 2; n++) {
      #pragma unroll
      for (int r = 0; r < 4; r++) {
        size_t rr = row0 + wr + m * 16 + cr + r;
        size_t cc = col0 + wc + n * 16 + cc0;
        C[rr * 512 + cc] = acc[m][n][r] + bias[cc];
      }
    }
  }
}

// ---------------- fused per-layer weight cast --------------------------------
__global__ void castw_kernel(const float* __restrict__ wq, const float* __restrict__ wk,
                             const float* __restrict__ wv, const float* __restrict__ wo,
                             const float* __restrict__ c1, const float* __restrict__ c2,
                             bf16* __restrict__ wqkv, bf16* __restrict__ wob,
                             bf16* __restrict__ c1b, bf16* __restrict__ c2b) {
  int i = blockIdx.x * 256 + threadIdx.x;
  if (i >= 786432) return;
  const float* s;
  bf16* d;
  int j;
  if (i < 196608) {
    s = (i < 65536) ? wq : (i < 131072) ? wk : wv;
    float4 v = ((const float4*)s)[i & 65535];
    d = wqkv + (size_t)i * 4;
    d[0] = __float2bfloat16(v.x); d[1] = __float2bfloat16(v.y);
    d[2] = __float2bfloat16(v.z); d[3] = __float2bfloat16(v.w);
    return;
  }
  if (i < 262144) { s = wo; j = i - 196608; d = wob + (size_t)j * 4; }
  else if (i < 524288) { s = c1; j = i - 262144; d = c1b + (size_t)j * 4; }
  else { s = c2; j = i - 524288; d = c2b + (size_t)j * 4; }
  float4 v = ((const float4*)s)[j];
  d[0] = __float2bfloat16(v.x); d[1] = __float2bfloat16(v.y);
  d[2] = __float2bfloat16(v.z); d[3] = __float2bfloat16(v.w);
}

__global__ void catb3_kernel(const float* __restrict__ a, const float* __restrict__ b,
                             const float* __restrict__ c, float* __restrict__ d) {
  int i = blockIdx.x * 256 + threadIdx.x;
  if (i >= 1536) return;
  d[i] = (i < 512) ? a[i] : (i < 1024) ? b[i - 512] : c[i - 1024];
}

// dcw [o][c][k] -> wcol[o][k*512+c] bf16
__global__ void wperm_kernel(const float* __restrict__ w, bf16* __restrict__ wcol) {
  int i = blockIdx.x * 256 + threadIdx.x;
  if (i >= 512 * 1536) return;
  int o = i / 1536, r = i % 1536, k = r / 512, c = r % 512;
  wcol[i] = __float2bfloat16(w[o * 1536 + c * 3 + k]);
}

// tok_w [o][c][k] (c<64,k<3) -> [o][k*64+c] bf16
__global__ void tokperm_kernel(const float* __restrict__ w, bf16* __restrict__ d) {
  int i = blockIdx.x * 256 + threadIdx.x;
  if (i >= 512 * 192) return;
  int o = i / 192, r = i % 192, k = r / 64, c = r % 64;
  d[i] = __float2bfloat16(w[o * 192 + c * 3 + k]);
}

// PE table [1024][512] fp32
__global__ void pe_kernel(float* __restrict__ PE) {
  int t = blockIdx.x, o = threadIdx.x;
  int i2 = o >> 1;
  float div = expf((float)(2 * i2) * (-9.210340371976184f / 512.f));
  float ang = (float)t * div;
  PE[t * 512 + o] = (o & 1) ? cosf(ang) : sinf(ang);
}

// embedding im2col: x_enc -> [B*L, 192] bf16 (j = k*64+c), +1e-10
__global__ void im2col_e_kernel(const float* __restrict__ x, bf16* __restrict__ d,
                                int B, int L) {
  size_t i = (size_t)blockIdx.x * 256 + threadIdx.x;
  if (i >= (size_t)B * L * 192) return;
  int j = (int)(i % 192);
  size_t row = i / 192;
  int k = j >> 6, c = j & 63;
  int t = (int)(row % L), b = (int)(row / L);
  int ts = (t - 1 + k) & (L - 1);
  d[i] = __float2bfloat16(x[((size_t)(b * L + ts)) * 64 + c] + 1e-10f);
}

// ---------------- sparsity measure M: XCD-pinned, 8-lane-per-u dots ---------
__global__ __launch_bounds__(256) void sparsity_kernel(
    const float* __restrict__ QKV, const int* __restrict__ idx,
    float* __restrict__ M, int B, int H, int L, int U) {
  int tpb = L >> 2;
  int xcd = blockIdx.x & 7, slot = blockIdx.x >> 3;
  int bh = xcd + ((slot / tpb) << 3);
  int tb = slot % tpb;
  int wave = threadIdx.x >> 6;
  int t = tb * 4 + wave;
  int lane = threadIdx.x & 63;
  int h = bh & 7, b = bh >> 3;
  int ul = lane >> 3;
  int j = lane & 7;
  const float* qrow = QKV + ((size_t)(b * L + t)) * 1536 + h * 64 + j * 8;
  float4 qa = *(const float4*)qrow;
  float4 qb = *(const float4*)(qrow + 4);
  const float* kbase = QKV + (size_t)b * L * 1536 + 512 + h * 64 + j * 8;
  const int* irow = idx + t * U;
  float mx = -INFINITY, sm = 0.f;
  int iters = (U + 7) >> 3;
  for (int i = 0; i < iters; i++) {
    int u = i * 8 + ul;
    bool valid = (u < U);
    int kt = valid ? irow[u] : 0;
    const float* kr = kbase + (size_t)kt * 1536;
    float4 ka = *(const float4*)kr;
    float4 kb = *(const float4*)(kr + 4);
    float part = qa.x * ka.x + qa.y * ka.y + qa.z * ka.z + qa.w * ka.w +
                 qb.x * kb.x + qb.y * kb.y + qb.z * kb.z + qb.w * kb.w;
    #pragma unroll
    for (int off = 1; off < 8; off <<= 1) part += __shfl_xor(part, off);
    if (valid) { mx = fmaxf(mx, part); sm += part; }
  }
  #pragma unroll
  for (int off = 8; off < 64; off <<= 1) {
    mx = fmaxf(mx, __shfl_xor(mx, off));
    sm += __shfl_xor(sm, off);
  }
  if (lane == 0) M[(size_t)bh * L + t] = mx - sm / (float)L;
}

// ---------------- top-k: 1024 threads/block, value-in-register argmax -------
__global__ __launch_bounds__(1024) void topk_kernel(
    const float* __restrict__ M, int* __restrict__ top, int L, int U) {
  __shared__ float wv[16];
  __shared__ int wi[16];
  __shared__ int best_s;
  int bh = blockIdx.x, tid = threadIdx.x;
  int lane = tid & 63, w = tid >> 6;
  float v = (tid < L) ? M[(size_t)bh * L + tid] : -INFINITY;
  int myt = tid;
  for (int it = 0; it < U; it++) {
    float bv = v;
    int bi = myt;
    #pragma unroll
    for (int off = 32; off; off >>= 1) {
      float ov = __shfl_xor(bv, off);
      int oi = __shfl_xor(bi, off);
      if (ov > bv || (ov == bv && oi < bi)) { bv = ov; bi = oi; }
    }
    if (lane == 0) { wv[w] = bv; wi[w] = bi; }
    __syncthreads();
    if (w == 0) {
      float v2 = (lane < 16) ? wv[lane] : -INFINITY;
      int i2 = (lane < 16) ? wi[lane] : 0x7fffffff;
      #pragma unroll
      for (int off = 8; off; off >>= 1) {
        float ov = __shfl_xor(v2, off);
        int oi = __shfl_xor(i2, off);
        if (ov > v2 || (ov == v2 && oi < i2)) { v2 = ov; i2 = oi; }
      }
      if (lane == 0) { best_s = i2; top[bh * U + it] = i2; }
    }
    __syncthreads();
    if (myt == best_s) v = -INFINITY;
  }
}

// ---------------- V mean: deterministic 2-stage (QKV stride 1536) -----------
__global__ __launch_bounds__(512) void vmean_part_kernel(
    const float* __restrict__ QKV, float* __restrict__ VP, int L, int segs) {
  int b = blockIdx.x, s = blockIdx.y, c = threadIdx.x;
  int per = L / segs;
  const float* vb = QKV + ((size_t)(b * L + s * per)) * 1536 + 1024 + c;
  float acc = 0.f;
  for (int t = 0; t < per; t++) acc += vb[(size_t)t * 1536];
  VP[((size_t)(b * segs + s)) * 512 + c] = acc;
}

__global__ void vmean_reduce_kernel(const float* __restrict__ VP, float* __restrict__ Vmean,
                                    int segs, int L) {
  int i = blockIdx.x * 256 + threadIdx.x;
  if (i >= 8 * 512) return;
  int b = i >> 9, c = i & 511;
  float acc = 0.f;
  for (int s = 0; s < segs; s++) acc += VP[((size_t)(b * segs + s)) * 512 + c];
  Vmean[i] = acc / (float)L;
}

// ---------------- broadcast ctx = Vmean (bf16 out) ---------------------------
__global__ void bcast_ctx_kernel(const float* __restrict__ Vmean, bf16* __restrict__ ATTb,
                                 int B, int L) {
  size_t i = (size_t)blockIdx.x * 256 + threadIdx.x;
  if (i >= (size_t)B * L * 512) return;
  int c = (int)(i % 512);
  int b = (int)(i / ((size_t)512 * L));
  ATTb[i] = __float2bfloat16(Vmean[b * 512 + c]);
}

// ---------------- split-K MFMA flash attention: partial pass ----------------
__global__ __launch_bounds__(256) void attn_partial_kernel(
    const float* __restrict__ QKV, const int* __restrict__ top,
    float* __restrict__ PCTX, float* __restrict__ PML,
    int B, int H, int L, int U, int SPLIT) {
  __shared__ short q_lds[64 * 72];
  __shared__ short k_lds[64 * 72];
  __shared__ short vt_lds[64 * 72];
  __shared__ short p_lds[4][16 * 72];
  int bh = blockIdx.x / SPLIT;
  int sp = blockIdx.x % SPLIT;
  int KS = L / SPLIT;
  int h = bh & 7, b = bh >> 3;
  int tid = threadIdx.x;
  int lane = tid & 63, w = tid >> 6;
  int r = tid >> 2, q4 = tid & 3, c0 = q4 << 4;
  int fr = lane & 15, fk = (lane >> 4) << 3, g = lane >> 4;

  {
    short tmp[16];
    if (r < U) {
      int tq = top[bh * U + r];
      const float* src = QKV + ((size_t)(b * L + tq)) * 1536 + h * 64 + c0;
      #pragma unroll
      for (int i = 0; i < 4; i++) {
        float4 v = ((const float4*)src)[i];
        tmp[i * 4 + 0] = f2bs(v.x); tmp[i * 4 + 1] = f2bs(v.y);
        tmp[i * 4 + 2] = f2bs(v.z); tmp[i * 4 + 3] = f2bs(v.w);
      }
    } else {
      #pragma unroll
      for (int i = 0; i < 16; i++) tmp[i] = 0;
    }
    *(bf16x8*)&q_lds[r * 72 + c0] = *(bf16x8*)&tmp[0];
    *(bf16x8*)&q_lds[r * 72 + c0 + 8] = *(bf16x8*)&tmp[8];
  }
  __syncthreads();
  bf16x8 aq0 = *(const bf16x8*)&q_lds[(w * 16 + fr) * 72 + fk];
  bf16x8 aq1 = *(const bf16x8*)&q_lds[(w * 16 + fr) * 72 + 32 + fk];

  f32x4 ctx[4] = {};
  float m_run[4], l_run[4];
  #pragma unroll
  for (int i = 0; i < 4; i++) { m_run[i] = -INFINITY; l_run[i] = 0.f; }

  for (int t0 = sp * KS; t0 < sp * KS + KS; t0 += 64) {
    __syncthreads();
    {
      const float* ks = QKV + ((size_t)(b * L + t0 + r)) * 1536 + 512 + h * 64 + c0;
      const float* vs = ks + 512;
      short kt[16];
      #pragma unroll
      for (int i = 0; i < 4; i++) {
        float4 v = ((const float4*)ks)[i];
        kt[i * 4 + 0] = f2bs(v.x); kt[i * 4 + 1] = f2bs(v.y);
        kt[i * 4 + 2] = f2bs(v.z); kt[i * 4 + 3] = f2bs(v.w);
      }
      *(bf16x8*)&k_lds[r * 72 + c0] = *(bf16x8*)&kt[0];
      *(bf16x8*)&k_lds[r * 72 + c0 + 8] = *(bf16x8*)&kt[8];
      #pragma unroll
      for (int i = 0; i < 4; i++) {
        float4 v = ((const float4*)vs)[i];
        vt_lds[(c0 + i * 4 + 0) * 72 + r] = f2bs(v.x);
        vt_lds[(c0 + i * 4 + 1) * 72 + r] = f2bs(v.y);
        vt_lds[(c0 + i * 4 + 2) * 72 + r] = f2bs(v.z);
        vt_lds[(c0 + i * 4 + 3) * 72 + r] = f2bs(v.w);
      }
    }
    __syncthreads();
    f32x4 s[4];
    #pragma unroll
    for (int n = 0; n < 4; n++) {
      bf16x8 b0 = *(const bf16x8*)&k_lds[(n * 16 + fr) * 72 + fk];
      bf16x8 b1 = *(const bf16x8*)&k_lds[(n * 16 + fr) * 72 + 32 + fk];
      f32x4 z = {};
      z = __builtin_amdgcn_mfma_f32_16x16x32_bf16(aq0, b0, z, 0, 0, 0);
      s[n] = __builtin_amdgcn_mfma_f32_16x16x32_bf16(aq1, b1, z, 0, 0, 0);
    }
    #pragma unroll
    for (int n = 0; n < 4; n++)
      #pragma unroll
      for (int rg = 0; rg < 4; rg++) s[n][rg] *= 0.125f;
    #pragma unroll
    for (int rg = 0; rg < 4; rg++) {
      float tm = fmaxf(fmaxf(s[0][rg], s[1][rg]), fmaxf(s[2][rg], s[3][rg]));
      #pragma unroll
      for (int off = 1; off < 16; off <<= 1) tm = fmaxf(tm, __shfl_xor(tm, off));
      float mnew = fmaxf(m_run[rg], tm);
      float sc_old = expf(m_run[rg] - mnew);
      float rowsum = 0.f;
      #pragma unroll
      for (int n = 0; n < 4; n++) {
        float p = expf(s[n][rg] - mnew);
        s[n][rg] = p;
        rowsum += p;
      }
      #pragma unroll
      for (int off = 1; off < 16; off <<= 1) rowsum += __shfl_xor(rowsum, off);
      l_run[rg] = l_run[rg] * sc_old + rowsum;
      m_run[rg] = mnew;
      #pragma unroll
      for (int nd = 0; nd < 4; nd++) ctx[nd][rg] *= sc_old;
    }
    short* pw = p_lds[w];
    #pragma unroll
    for (int n = 0; n < 4; n++)
      #pragma unroll
      for (int rg = 0; rg < 4; rg++)
        pw[(g * 4 + rg) * 72 + n * 16 + fr] = f2bs(s[n][rg]);
    bf16x8 pa0 = *(const bf16x8*)&pw[fr * 72 + fk];
    bf16x8 pa1 = *(const bf16x8*)&pw[fr * 72 + 32 + fk];
    #pragma unroll
    for (int nd = 0; nd < 4; nd++) {
      bf16x8 v0 = *(const bf16x8*)&vt_lds[(nd * 16 + fr) * 72 + fk];
      bf16x8 v1 = *(const bf16x8*)&vt_lds[(nd * 16 + fr) * 72 + 32 + fk];
      ctx[nd] = __builtin_amdgcn_mfma_f32_16x16x32_bf16(pa0, v0, ctx[nd], 0, 0, 0);
      ctx[nd] = __builtin_amdgcn_mfma_f32_16x16x32_bf16(pa1, v1, ctx[nd], 0, 0, 0);
    }
  }
  #pragma unroll
  for (int rg = 0; rg < 4; rg++) {
    int qq = w * 16 + g * 4 + rg;
    if (qq < U) {
      size_t base = ((size_t)bh * SPLIT + sp) * 64 + qq;
      #pragma unroll
      for (int nd = 0; nd < 4; nd++)
        PCTX[base * 64 + nd * 16 + fr] = ctx[nd][rg];
      if (fr == 0) {
        PML[base * 2] = m_run[rg];
        PML[base * 2 + 1] = l_run[rg];
      }
    }
  }
}

// ---------------- split-K combine: merge SPLIT partials, write ATTb ---------
__global__ __launch_bounds__(256) void attn_combine_kernel(
    const float* __restrict__ PCTX, const float* __restrict__ PML,
    const int* __restrict__ top, bf16* __restrict__ ATTb,
    int B, int H, int L, int U, int SPLIT) {
  int bh = blockIdx.x;
  int row = blockIdx.y * 4 + (threadIdx.x >> 6);
  int d = threadIdx.x & 63;
  if (row >= U) return;
  int h = bh & 7, b = bh >> 3;
  float mstar = -INFINITY;
  for (int sp = 0; sp < SPLIT; sp++)
    mstar = fmaxf(mstar, PML[(((size_t)bh * SPLIT + sp) * 64 + row) * 2]);
  float lstar = 0.f, cacc = 0.f;
  for (int sp = 0; sp < SPLIT; sp++) {
    size_t base = ((size_t)bh * SPLIT + sp) * 64 + row;
    float m = PML[base * 2], lv = PML[base * 2 + 1];
    float wgt = expf(m - mstar);
    lstar += lv * wgt;
    cacc += PCTX[base * 64 + d] * wgt;
  }
  int tq = top[bh * U + row];
  ATTb[((size_t)(b * L + tq)) * 512 + h * 64 + d] = __float2bfloat16(cacc / lstar);
}

// ---------------- row LayerNorm (shuffle-reduce, 2 barriers) -----------------
__global__ __launch_bounds__(256) void ln_kernel(
    const float* __restrict__ Xin, const float* __restrict__ g,
    const float* __restrict__ bta, float* __restrict__ Xout,
    bf16* __restrict__ Xoutb, int rows) {
  __shared__ float part[8];
  int r = blockIdx.x, tid = threadIdx.x;
  int lane = tid & 63, w = tid >> 6;
  const float* xr = Xin + (size_t)r * 512;
  float v0 = xr[tid], v1 = xr[tid + 256];
  float s = v0 + v1;
  #pragma unroll
  for (int off = 1; off < 64; off <<= 1) s += __shfl_xor(s, off);
  if (lane == 0) part[w] = s;
  __syncthreads();
  float mean = (part[0] + part[1] + part[2] + part[3]) * (1.f / 512.f);
  float d0 = v0 - mean, d1 = v1 - mean;
  float q = d0 * d0 + d1 * d1;
  #pragma unroll
  for (int off = 1; off < 64; off <<= 1) q += __shfl_xor(q, off);
  if (lane == 0) part[4 + w] = q;
  __syncthreads();
  float var = (part[4] + part[5] + part[6] + part[7]) * (1.f / 512.f);
  float rs = rsqrtf(var + 1e-5f);
  float o0 = d0 * rs * g[tid] + bta[tid];
  float o1 = d1 * rs * g[tid + 256] + bta[tid + 256];
  float* out = Xout + (size_t)r * 512;
  out[tid] = o0;
  out[tid + 256] = o1;
  if (Xoutb) {
    Xoutb[(size_t)r * 512 + tid] = __float2bfloat16(o0);
    Xoutb[(size_t)r * 512 + tid + 256] = __float2bfloat16(o1);
  }
}

// ---------------- BatchNorm stats -------------------------------------------
__global__ void zero_kernel(float* p, int n) {
  int i = blockIdx.x * 256 + threadIdx.x;
  if (i < n) p[i] = 0.f;
}

__global__ __launch_bounds__(256) void bnstat_kernel(
    const float* __restrict__ Y, float* __restrict__ acc, int rows) {
  int tid = threadIdx.x;
  int c0 = tid, c1 = tid + 256;
  float s0 = 0, s1 = 0, q0 = 0, q1 = 0;
  for (int r = blockIdx.x; r < rows; r += gridDim.x) {
    float v0 = Y[(size_t)r * 512 + c0];
    float v1 = Y[(size_t)r * 512 + c1];
    s0 += v0; q0 += v0 * v0;
    s1 += v1; q1 += v1 * v1;
  }
  atomicAdd(&acc[c0], s0);
  atomicAdd(&acc[c1], s1);
  atomicAdd(&acc[512 + c0], q0);
  atomicAdd(&acc[512 + c1], q1);
}

// ---------------- fused BN + ELU + MaxPool(3,2,1) (+bf16 out) ---------------
__global__ void bnpool_kernel(const float* __restrict__ Y, const float* __restrict__ acc,
                              const float* __restrict__ g, const float* __restrict__ be,
                              float* __restrict__ Xout, bf16* __restrict__ Xoutb,
                              int B, int L, int rows) {
  int Lout = L / 2;
  size_t i = (size_t)blockIdx.x * 256 + threadIdx.x;
  if (i >= (size_t)B * Lout * 512) return;
  int c = (int)(i % 512);
  size_t orow = i / 512;
  int to = (int)(orow % Lout), b = (int)(orow / Lout);
  float mu = acc[c] / (float)rows;
  float var = acc[512 + c] / (float)rows - mu * mu;
  float rs = rsqrtf(var + 1e-5f) * g[c];
  float mx = -INFINITY;
  #pragma unroll
  for (int dj = -1; dj <= 1; dj++) {
    int j = 2 * to + dj;
    if (j < 0 || j >= L) continue;
    float v = (Y[((size_t)(b * L + j)) * 512 + c] - mu) * rs + be[c];
    v = v > 0.f ? v : expm1f(v);
    mx = fmaxf(mx, v);
  }
  Xout[i] = mx;
  Xoutb[i] = __float2bfloat16(mx);
}

// ---------------- final mean over rows: 2-stage ------------------------------
__global__ void meanrows_part_kernel(const float* __restrict__ Xin, float* __restrict__ MP,
                                     int L, int segs) {
  int b = blockIdx.x, s = blockIdx.y, d = threadIdx.x;
  int per = L / segs;
  const float* base = Xin + ((size_t)(b * L + s * per)) * 512 + d;
  float acc = 0.f;
  for (int t = 0; t < per; t++) acc += base[(size_t)t * 512];
  MP[((size_t)(b * segs + s)) * 512 + d] = acc;
}

__global__ void meanrows_red_kernel(const float* __restrict__ MP, float* __restrict__ out,
                                    int segs, int L) {
  int i = blockIdx.x * 256 + threadIdx.x;
  if (i >= 8 * 512) return;
  int b = i >> 9, c = i & 511;
  float acc = 0.f;
  for (int s = 0; s < segs; s++) acc += MP[((size_t)(b * segs + s)) * 512 + c];
  out[i] = acc / (float)L;
}

// ============================================================================
extern "C" void kernel_launch(void* const* d_in, const int* in_sizes, int n_in,
                              void* d_out, int out_size, void* d_ws, size_t ws_size,
                              hipStream_t stream) {
  const float* x_enc = (const float*)d_in[0];
  const float* tok_w = (const float*)d_in[1];
  const float* Wq = (const float*)d_in[2];
  const float* bq = (const float*)d_in[3];
  const float* Wk = (const float*)d_in[4];
  const float* bk = (const float*)d_in[5];
  const float* Wv = (const float*)d_in[6];
  const float* bv = (const float*)d_in[7];
  const float* Wo = (const float*)d_in[8];
  const float* bo = (const float*)d_in[9];
  const float* c1w = (const float*)d_in[10];
  const float* c1b = (const float*)d_in[11];
  const float* c2w = (const float*)d_in[12];
  const float* c2b = (const float*)d_in[13];
  const float* n1g = (const float*)d_in[14];
  const float* n1b = (const float*)d_in[15];
  const float* n2g = (const float*)d_in[16];
  const float* n2b = (const float*)d_in[17];
  const float* dcw = (const float*)d_in[18];
  const float* dcb = (const float*)d_in[19];
  const float* bng = (const float*)d_in[20];
  const float* bnb = (const float*)d_in[21];
  const float* fng = (const float*)d_in[22];
  const float* fnb = (const float*)d_in[23];

  const int B = 8, H = 8;
  const size_t NX = 4194304;  // 8*1024*512

  float* ws = (float*)d_ws;
  float* X    = ws;
  float* XLN  = ws + NX;                 // dead during attention -> PART bufs
  float* PCTX = XLN;
  float* PML  = XLN + 2097152;
  float* QKVf = ws + 2 * NX;
  bf16* H2b   = (bf16*)(ws + 2 * NX);
  float* Yc   = ws + 2 * NX;
  bf16* INb   = (bf16*)(ws + 5 * NX);
  bf16* ATTb  = (bf16*)(ws + 5 * NX + NX / 2);
  float* WB   = ws + 6 * NX;
  bf16* WQKVb = (bf16*)(WB);
  bf16* Wob  = (bf16*)(WB + 393216);
  bf16* c1wb = (bf16*)(WB + 524288);
  bf16* c2wb = (bf16*)(WB + 1048576);
  bf16* wcvb = (bf16*)(WB + 1572864);
  bf16* tokwb = (bf16*)(WB + 1966080);
  float* PE   = WB + 2015232;
  float* MBUF = PE + 524288;
  float* VMEAN = MBUF + 65536;
  float* BNACC = VMEAN + 4096;
  int* IDX = (int*)(BNACC + 1024);
  int* TOP = IDX + 35840;
  float* VPART = (float*)(TOP + 2240);
  float* BQKV = VPART + 131072;

  // ---- embedding as GEMM (fused bf16 cast via outmode=1) ----
  pe_kernel<<<1024, 512, 0, stream>>>(PE);
  tokperm_kernel<<<(512 * 192 + 255) / 256, 256, 0, stream>>>(tok_w, tokwb);
  im2col_e_kernel<<<(int)(((size_t)B * 1024 * 192 + 255) / 256), 256, 0, stream>>>(
      x_enc, INb, B, 1024);
  bgemm_g<<<dim3(128, 8), 256, 0, stream>>>(INb, tokwb, nullptr, PE, 1024,
                                            X, INb, 8192, 512, 192, 0, 1);

  int L = 1024;
  for (int l = 0; l < 3; l++) {
    int U = (L == 256) ? 30 : 35;
    int SPLIT = (L >= 512) ? 8 : 4;
    int rows = B * L;
    dim3 g64(rows / 64, 8);

    castw_kernel<<<3072, 256, 0, stream>>>(
        Wq + (size_t)l * 262144, Wk + (size_t)l * 262144, Wv + (size_t)l * 262144,
        Wo + (size_t)l * 262144, c1w + (size_t)l * 1048576, c2w + (size_t)l * 1048576,
        WQKVb, Wob, c1wb, c2wb);
    catb3_kernel<<<6, 256, 0, stream>>>(bq + l * 512, bk + l * 512, bv + l * 512, BQKV);
    if (l < 2)
      wperm_kernel<<<3072, 256, 0, stream>>>(dcw + (size_t)l * 786432, wcvb);

    // merged QKV projection: [rows,1536]
    bgemm_g<<<dim3(rows / 64, 24), 256, 0, stream>>>(
        INb, WQKVb, BQKV, nullptr, 0, QKVf, nullptr, rows, 1536, 512, 0, 0);

    int half = L * U / 2;
    idx_kernel<<<(half + 255) / 256, 256, 0, stream>>>(IDX, L, U, l);
    sparsity_kernel<<<(B * H * L) / 4, 256, 0, stream>>>(QKVf, IDX, MBUF, B, H, L, U);
    topk_kernel<<<B * H, 1024, 0, stream>>>(MBUF, TOP, L, U);
    vmean_part_kernel<<<dim3(B, 32), 512, 0, stream>>>(QKVf, VPART, L, 32);
    vmean_reduce_kernel<<<16, 256, 0, stream>>>(VPART, VMEAN, 32, L);
    bcast_ctx_kernel<<<(rows * 512) / 256, 256, 0, stream>>>(VMEAN, ATTb, B, L);
    attn_partial_kernel<<<B * H * SPLIT, 256, 0, stream>>>(
        QKVf, TOP, PCTX, PML, B, H, L, U, SPLIT);
    attn_combine_kernel<<<dim3(B * H, (U + 3) / 4), 256, 0, stream>>>(
        PCTX, PML, TOP, ATTb, B, H, L, U, SPLIT);

    bgemm_g<<<g64, 256, 0, stream>>>(ATTb, Wob, bo + l * 512, X, 0,
                                     X, nullptr, rows, 512, 512, 0, 0);
    ln_kernel<<<rows, 256, 0, stream>>>(X, n1g + l * 512, n1b + l * 512, XLN, INb, rows);
    bgemm_g<<<dim3(rows / 64, 32), 256, 0, stream>>>(
        INb, c1wb, c1b + l * 2048, nullptr, 0, nullptr, H2b, rows, 2048, 512, 1, 2);
    bgemm_g<<<g64, 256, 0, stream>>>(H2b, c2wb, c2b + l * 512, XLN, 0,
                                     X, nullptr, rows, 512, 2048, 0, 0);
    // ln2: also emit bf16 X for fused conv staging when a distil conv follows
    ln_kernel<<<rows, 256, 0, stream>>>(X, n2g + l * 512, n2b + l * 512, X,
                                        (l < 2) ? INb : nullptr, rows);

    if (l < 2) {
      bgemm_conv<<<g64, 256, 0, stream>>>(INb, wcvb, dcb + l * 512, Yc, rows, L);
      zero_kernel<<<4, 256, 0, stream>>>(BNACC, 1024);
      bnstat_kernel<<<128, 256, 0, stream>>>(Yc, BNACC, rows);
      bnpool_kernel<<<(rows / 2 * 512) / 256, 256, 0, stream>>>(
          Yc, BNACC, bng + l * 512, bnb + l * 512, X, INb, B, L, rows);
      L >>= 1;
    }
  }

  int rowsF = B * L;  // L = 256
  ln_kernel<<<rowsF, 256, 0, stream>>>(X, fng, fnb, XLN, nullptr, rowsF);
  meanrows_part_kernel<<<dim3(8, 8), 512, 0, stream>>>(XLN, VPART, L, 8);
  meanrows_red_kernel<<<16, 256, 0, stream>>>(VPART, (float*)d_out, 8, L);
}